// Round 9
// baseline (385.882 us; speedup 1.0000x reference)
//
#include <hip/hip_runtime.h>
#include <math.h>

// ---------------- problem constants ----------------
#define TSEQ 2048
#define DD   512
#define NH   8
#define HSZ  64
#define NE   8
#define NTOK 8192    // B*T
#define CAPK 2048
#define FF   2048    // 4*D

typedef __bf16 bf16x8 __attribute__((ext_vector_type(8)));
typedef float  f32x4  __attribute__((ext_vector_type(4)));
typedef unsigned int u32;
typedef u32 u32x2 __attribute__((ext_vector_type(2)));
typedef short s16x4 __attribute__((ext_vector_type(4)));

// counted vector-memory wait (T4): keep younger prefetch loads in flight
#define WAITVM(N) asm volatile("s_waitcnt vmcnt(" #N ")" ::: "memory")

__device__ __forceinline__ void gload16(const void* g, void* l){
  __builtin_amdgcn_global_load_lds((const __attribute__((address_space(1))) u32*)g,
                                   (__attribute__((address_space(3))) u32*)l, 16, 0, 0);
}

__device__ __forceinline__ u32 pkbf(float a, float b){
  unsigned short ua = __builtin_bit_cast(unsigned short, (__bf16)a);
  unsigned short ub = __builtin_bit_cast(unsigned short, (__bf16)b);
  return (u32)ua | ((u32)ub << 16);
}

__device__ __forceinline__ s16x4 mk4(u32 a, u32 b){
  u32x2 t; t[0] = a; t[1] = b;
  return __builtin_bit_cast(s16x4, t);
}

// ============================================================
// Threefry-2x32, key = (0, 42)
// ============================================================
__device__ __forceinline__ unsigned rotl32(unsigned x, int r){ return (x<<r)|(x>>(32-r)); }

__device__ __forceinline__ void threefry2x32(unsigned c0, unsigned c1, unsigned &o0, unsigned &o1){
  const unsigned k0 = 0u, k1 = 42u;
  const unsigned k2 = k0 ^ k1 ^ 0x1BD11BDAu;
  unsigned x0 = c0 + k0, x1 = c1 + k1;
#define TFR(rot) { x0 += x1; x1 = rotl32(x1, rot); x1 ^= x0; }
  TFR(13) TFR(15) TFR(26) TFR(6)   x0 += k1; x1 += k2 + 1u;
  TFR(17) TFR(29) TFR(16) TFR(24)  x0 += k2; x1 += k0 + 2u;
  TFR(13) TFR(15) TFR(26) TFR(6)   x0 += k0; x1 += k1 + 3u;
  TFR(17) TFR(29) TFR(16) TFR(24)  x0 += k1; x1 += k2 + 4u;
  TFR(13) TFR(15) TFR(26) TFR(6)   x0 += k2; x1 += k0 + 5u;
#undef TFR
  o0 = x0; o1 = x1;
}

__device__ __forceinline__ float erfinv_f(float x){
  float w = -log1pf(-x*x);
  float p;
  if (w < 5.0f){
    w -= 2.5f;
    p = 2.81022636e-08f;
    p = fmaf(p,w, 3.43273939e-07f);
    p = fmaf(p,w,-3.5233877e-06f);
    p = fmaf(p,w,-4.39150654e-06f);
    p = fmaf(p,w, 0.00021858087f);
    p = fmaf(p,w,-0.00125372503f);
    p = fmaf(p,w,-0.00417768164f);
    p = fmaf(p,w, 0.246640727f);
    p = fmaf(p,w, 1.50140941f);
  } else {
    w = sqrtf(w) - 3.0f;
    p = -0.000200214257f;
    p = fmaf(p,w, 0.000100950558f);
    p = fmaf(p,w, 0.00134934322f);
    p = fmaf(p,w,-0.00367342844f);
    p = fmaf(p,w, 0.00573950773f);
    p = fmaf(p,w,-0.0076224613f);
    p = fmaf(p,w, 0.00943887047f);
    p = fmaf(p,w, 1.00167406f);
    p = fmaf(p,w, 2.83297682f);
  }
  return p * x;
}

// ============================================================
// LayerNorm -> hi/lo bf16 (LN1)
// ============================================================
__global__ __launch_bounds__(256) void ln_split(const float* __restrict__ x,
    const float* __restrict__ gw, const float* __restrict__ bw,
    __bf16* __restrict__ ohi, __bf16* __restrict__ olo)
{
  int row  = blockIdx.x*4 + threadIdx.y;
  int lane = threadIdx.x;
  const float* xr = x + (size_t)row*DD;
  float4 a = *(const float4*)(xr + lane*4);
  float4 c = *(const float4*)(xr + 256 + lane*4);
  float s  = a.x+a.y+a.z+a.w + c.x+c.y+c.z+c.w;
  float ss = a.x*a.x+a.y*a.y+a.z*a.z+a.w*a.w + c.x*c.x+c.y*c.y+c.z*c.z+c.w*c.w;
  #pragma unroll
  for (int off = 32; off; off >>= 1){ s += __shfl_xor(s, off); ss += __shfl_xor(ss, off); }
  float m   = s * (1.0f/DD);
  float var = ss * (1.0f/DD) - m*m;
  float r   = 1.0f / sqrtf(var + 1e-5f);
  float4 g1 = *(const float4*)(gw + lane*4);
  float4 b1 = *(const float4*)(bw + lane*4);
  float4 g2 = *(const float4*)(gw + 256 + lane*4);
  float4 b2 = *(const float4*)(bw + 256 + lane*4);
  float f1[4], f2[4];
  f1[0]=(a.x-m)*r*g1.x+b1.x; f1[1]=(a.y-m)*r*g1.y+b1.y; f1[2]=(a.z-m)*r*g1.z+b1.z; f1[3]=(a.w-m)*r*g1.w+b1.w;
  f2[0]=(c.x-m)*r*g2.x+b2.x; f2[1]=(c.y-m)*r*g2.y+b2.y; f2[2]=(c.z-m)*r*g2.z+b2.z; f2[3]=(c.w-m)*r*g2.w+b2.w;
  __bf16 h1v[4] __attribute__((aligned(8))), l1v[4] __attribute__((aligned(8)));
  __bf16 h2v[4] __attribute__((aligned(8))), l2v[4] __attribute__((aligned(8)));
  #pragma unroll
  for (int j = 0; j < 4; ++j){
    __bf16 hb = (__bf16)f1[j]; h1v[j]=hb; l1v[j]=(__bf16)(f1[j]-(float)hb);
    __bf16 hc = (__bf16)f2[j]; h2v[j]=hc; l2v[j]=(__bf16)(f2[j]-(float)hc);
  }
  size_t base = (size_t)row*DD + lane*4;
  *(uint2*)(ohi + base)       = *(const uint2*)h1v;
  *(uint2*)(olo + base)       = *(const uint2*)l1v;
  *(uint2*)(ohi + base + 256) = *(const uint2*)h2v;
  *(uint2*)(olo + base + 256) = *(const uint2*)l2v;
}

// ============================================================
// Pack Wq|Wk|Wv (H,D,HS) -> transposed hi/lo bf16 [1536][512]
// ============================================================
__global__ __launch_bounds__(256) void pack_qkv_split(const float* __restrict__ Wq,
    const float* __restrict__ Wk, const float* __restrict__ Wv,
    __bf16* __restrict__ dhi, __bf16* __restrict__ dlo)
{
  __shared__ float t[64][65];
  int z = blockIdx.y;
  int kt = blockIdx.x*64;
  int sel = z >> 3, hh = z & 7;
  const float* W = (sel==0 ? Wq : (sel==1 ? Wk : Wv)) + (size_t)hh*DD*HSZ;
  int tid = threadIdx.x;
  int r = tid>>2, c0 = (tid&3)*16;
  #pragma unroll
  for (int j = 0; j < 16; j += 4){
    float4 v = *(const float4*)&W[(size_t)(kt+r)*HSZ + c0 + j];
    t[r][c0+j]=v.x; t[r][c0+j+1]=v.y; t[r][c0+j+2]=v.z; t[r][c0+j+3]=v.w;
  }
  __syncthreads();
  __bf16 hb[16] __attribute__((aligned(32)));
  __bf16 lb[16] __attribute__((aligned(32)));
  #pragma unroll
  for (int j = 0; j < 16; ++j){
    float f = t[c0+j][r];
    __bf16 h = (__bf16)f; hb[j]=h; lb[j]=(__bf16)(f-(float)h);
  }
  size_t off = (size_t)(z*64 + r)*512 + kt + c0;
  *(uint4*)(dhi+off) = ((const uint4*)hb)[0]; *(uint4*)(dhi+off+8) = ((const uint4*)hb)[1];
  *(uint4*)(dlo+off) = ((const uint4*)lb)[0]; *(uint4*)(dlo+off+8) = ((const uint4*)lb)[1];
}

// ============================================================
// Generic transpose + hi/lo split (Wo)
// ============================================================
__global__ __launch_bounds__(256) void transp_split(const float* __restrict__ src,
    __bf16* __restrict__ dhi, __bf16* __restrict__ dlo, int Ms, int Ns)
{
  __shared__ float t[64][65];
  int nt = blockIdx.x*64, mt = blockIdx.y*64;
  int tid = threadIdx.x;
  int r = tid>>2, c0 = (tid&3)*16;
  #pragma unroll
  for (int j = 0; j < 16; j += 4){
    float4 v = *(const float4*)&src[(size_t)(mt+r)*Ns + nt + c0 + j];
    t[r][c0+j]=v.x; t[r][c0+j+1]=v.y; t[r][c0+j+2]=v.z; t[r][c0+j+3]=v.w;
  }
  __syncthreads();
  __bf16 hb[16] __attribute__((aligned(32)));
  __bf16 lb[16] __attribute__((aligned(32)));
  #pragma unroll
  for (int j = 0; j < 16; ++j){
    float f = t[c0+j][r];
    __bf16 h = (__bf16)f; hb[j]=h; lb[j]=(__bf16)(f-(float)h);
  }
  size_t off = (size_t)(nt + r)*Ms + mt + c0;
  *(uint4*)(dhi+off) = ((const uint4*)hb)[0]; *(uint4*)(dhi+off+8) = ((const uint4*)hb)[1];
  *(uint4*)(dlo+off) = ((const uint4*)lb)[0]; *(uint4*)(dlo+off+8) = ((const uint4*)lb)[1];
}

// ============================================================
// bf16x3 split-precision MFMA GEMM, 2-phase, counted-vmcnt pipeline.
// ============================================================
template<int BIAS, int RES>
__global__ __launch_bounds__(256) void gemm_mfma3(
    const __bf16* __restrict__ Ahi, const __bf16* __restrict__ Alo,
    const __bf16* __restrict__ Bhi, const __bf16* __restrict__ Blo,
    const float* __restrict__ bias, const float* __restrict__ res,
    float* __restrict__ C, int M, int N, int K)
{
  __shared__ __bf16 AsH[2][4096];
  __shared__ __bf16 AsL[2][4096];
  __shared__ __bf16 BsH[2][4096];
  __shared__ __bf16 BsL[2][4096];
  int m0 = blockIdx.y*128, n0 = blockIdx.x*128;
  int tid = threadIdx.x;
  int w = tid>>6, l = tid&63;
  int wm = w>>1, wn = w&1;
  int srow = w*32 + (l>>2);
  int skb  = (l&3)<<4;
  const char* agh = (const char*)(Ahi + (size_t)(m0+srow)*K) + skb;
  const char* agl = (const char*)(Alo + (size_t)(m0+srow)*K) + skb;
  const char* bgh = (const char*)(Bhi + (size_t)(n0+srow)*K) + skb;
  const char* bgl = (const char*)(Blo + (size_t)(n0+srow)*K) + skb;
  size_t r16 = (size_t)16*K*sizeof(__bf16);

  f32x4 acc[4][4] = {};
  int rl = l & 15, kh = l >> 4;
  const __bf16* abh = &AsH[0][(wm*64 + rl)*32 + kh*8];
  const __bf16* abl = &AsL[0][(wm*64 + rl)*32 + kh*8];
  const __bf16* bbh = &BsH[0][(wn*64 + rl)*32 + kh*8];
  const __bf16* bbl = &BsL[0][(wn*64 + rl)*32 + kh*8];

  auto STAGE = [&](int bb, int kt){
    size_t o = (size_t)kt*64;
    gload16(agh+o,     &AsH[bb][w*1024]);
    gload16(agh+o+r16, &AsH[bb][w*1024+512]);
    gload16(agl+o,     &AsL[bb][w*1024]);
    gload16(agl+o+r16, &AsL[bb][w*1024+512]);
    gload16(bgh+o,     &BsH[bb][w*1024]);
    gload16(bgh+o+r16, &BsH[bb][w*1024+512]);
    gload16(bgl+o,     &BsL[bb][w*1024]);
    gload16(bgl+o+r16, &BsL[bb][w*1024+512]);
  };

  int nkt = K >> 5;
  STAGE(0, 0);
  for (int kt = 0; kt < nkt; ++kt){
    int bb = kt & 1;
    if (kt + 1 < nkt){ STAGE(bb^1, kt+1); WAITVM(8); }
    else             { WAITVM(0); }
    __builtin_amdgcn_s_barrier();
    bf16x8 afh[4], afl[4], bfh[4], bfl[4];
    #pragma unroll
    for (int i = 0; i < 4; ++i){
      afh[i] = *(const bf16x8*)(abh + bb*4096 + i*512);
      afl[i] = *(const bf16x8*)(abl + bb*4096 + i*512);
      bfh[i] = *(const bf16x8*)(bbh + bb*4096 + i*512);
      bfl[i] = *(const bf16x8*)(bbl + bb*4096 + i*512);
    }
    #pragma unroll
    for (int fm = 0; fm < 4; ++fm)
      #pragma unroll
      for (int fn = 0; fn < 4; ++fn){
        acc[fm][fn] = __builtin_amdgcn_mfma_f32_16x16x32_bf16(afh[fm], bfl[fn], acc[fm][fn], 0, 0, 0);
        acc[fm][fn] = __builtin_amdgcn_mfma_f32_16x16x32_bf16(afl[fm], bfh[fn], acc[fm][fn], 0, 0, 0);
        acc[fm][fn] = __builtin_amdgcn_mfma_f32_16x16x32_bf16(afh[fm], bfh[fn], acc[fm][fn], 0, 0, 0);
      }
    __builtin_amdgcn_s_barrier();
  }

  int ccol = l & 15, cr = (l >> 4) * 4;
  #pragma unroll
  for (int fn = 0; fn < 4; ++fn){
    int n = n0 + wn*64 + fn*16 + ccol;
    float bv = BIAS ? bias[n] : 0.0f;
    #pragma unroll
    for (int fm = 0; fm < 4; ++fm){
      int mb = m0 + wm*64 + fm*16 + cr;
      #pragma unroll
      for (int r = 0; r < 4; ++r){
        float v = acc[fm][fn][r] + bv;
        if (RES) v += res[(size_t)(mb+r)*N + n];
        C[(size_t)(mb+r)*N + n] = v;
      }
    }
  }
}

// ============================================================
// bf16 MFMA GEMM (experts), 2-phase counted-vmcnt, 1-D grid with
// expert = flat & (2^EBITS-1) (XCD locality), optional gather-indirect A.
// ============================================================
template<int STORE_BF16, int RELU, int GATHER, int LOGN, int EBITS>
__global__ __launch_bounds__(256) void gemm_mfma(
    const __bf16* __restrict__ A, const __bf16* __restrict__ Bt,
    const float* __restrict__ bias, void* __restrict__ Cv,
    const int* __restrict__ idxb, int M, int N, int K)
{
  __shared__ __bf16 Asl[2][4096];
  __shared__ __bf16 Bsl[2][4096];
  int flat = blockIdx.x;
  int e = flat & ((1<<EBITS)-1);
  int tile = flat >> EBITS;
  int n0 = (tile & ((1<<LOGN)-1)) * 128;
  int m0 = (tile >> LOGN) * 128;
  const __bf16* Be = Bt + (size_t)e*N*K;
  const float*  be = bias + (size_t)e*N;
  int tid = threadIdx.x;
  int w = tid>>6, l = tid&63;
  int wm = w>>1, wn = w&1;
  int srow = w*32 + (l>>2);
  int skb  = (l&3)<<4;
  const char* ag;
  if (GATHER){
    int tok = idxb[e*CAPK + m0 + srow];
    ag = (const char*)(A + (size_t)tok*K) + skb;
  } else {
    ag = (const char*)(A + (size_t)e*M*K + (size_t)(m0 + srow)*K) + skb;
  }
  const char* bg = (const char*)(Be + (size_t)(n0 + srow)*K) + skb;
  size_t r16;
  if (GATHER){
    int tok2 = idxb[e*CAPK + m0 + srow + 16];
    r16 = (size_t)((const char*)(A + (size_t)tok2*K) + skb - ag);
  } else {
    r16 = (size_t)16*K*sizeof(__bf16);
  }

  f32x4 acc[4][4] = {};
  int rl = l & 15, kh = l >> 4;
  const __bf16* abase = &Asl[0][(wm*64 + rl)*32 + kh*8];
  const __bf16* bbase = &Bsl[0][(wn*64 + rl)*32 + kh*8];

  size_t br16 = (size_t)16*K*sizeof(__bf16);
  auto STAGE = [&](int bb, int kt){
    size_t o = (size_t)kt*64;
    gload16(ag+o,      &Asl[bb][w*1024]);
    gload16(ag+o+r16,  &Asl[bb][w*1024+512]);
    gload16(bg+o,      &Bsl[bb][w*1024]);
    gload16(bg+o+br16, &Bsl[bb][w*1024+512]);
  };

  int nkt = K >> 5;
  STAGE(0, 0);
  for (int kt = 0; kt < nkt; ++kt){
    int bb = kt & 1;
    if (kt + 1 < nkt){ STAGE(bb^1, kt+1); WAITVM(4); }
    else             { WAITVM(0); }
    __builtin_amdgcn_s_barrier();
    bf16x8 af[4], bf[4];
    #pragma unroll
    for (int i = 0; i < 4; ++i){
      af[i] = *(const bf16x8*)(abase + bb*4096 + i*512);
      bf[i] = *(const bf16x8*)(bbase + bb*4096 + i*512);
    }
    #pragma unroll
    for (int fm = 0; fm < 4; ++fm)
      #pragma unroll
      for (int fn = 0; fn < 4; ++fn)
        acc[fm][fn] = __builtin_amdgcn_mfma_f32_16x16x32_bf16(af[fm], bf[fn], acc[fm][fn], 0, 0, 0);
    __builtin_amdgcn_s_barrier();
  }

  int ccol = l & 15, cr = (l >> 4) * 4;
  char* Ce = (char*)Cv + (size_t)e*M*N*(STORE_BF16 ? 2 : 4);
  #pragma unroll
  for (int fn = 0; fn < 4; ++fn){
    int n = n0 + wn*64 + fn*16 + ccol;
    float bv = be[n];
    #pragma unroll
    for (int fm = 0; fm < 4; ++fm){
      int mb = m0 + wm*64 + fm*16 + cr;
      #pragma unroll
      for (int r = 0; r < 4; ++r){
        float v = acc[fm][fn][r] + bv;
        if (RELU) v = fmaxf(v, 0.f);
        if (STORE_BF16) ((__bf16*)Ce)[(size_t)(mb+r)*N + n] = (__bf16)v;
        else            ((float*)Ce)[(size_t)(mb+r)*N + n] = v;
      }
    }
  }
}

// ============================================================
// Transpose + convert expert weights (f32 -> plain bf16 [N][K])
// ============================================================
__global__ __launch_bounds__(256) void transp_conv(const float* __restrict__ src,
    __bf16* __restrict__ dst, int Ms, int Ns)
{
  __shared__ __bf16 t[64][72];
  int e = blockIdx.z;
  const float* s = src + (size_t)e*Ms*Ns;
  __bf16* d = dst + (size_t)e*Ms*Ns;
  int mt = blockIdx.y*64, nt = blockIdx.x*64;
  int tid = threadIdx.x;
  int r = tid>>2, c0 = (tid&3)*16;
  #pragma unroll
  for (int j = 0; j < 16; j += 4){
    float4 v = *(const float4*)&s[(size_t)(mt+r)*Ns + nt + c0 + j];
    t[r][c0+j]   = (__bf16)v.x; t[r][c0+j+1] = (__bf16)v.y;
    t[r][c0+j+2] = (__bf16)v.z; t[r][c0+j+3] = (__bf16)v.w;
  }
  __syncthreads();
  __bf16 tmp[16] __attribute__((aligned(32)));
  #pragma unroll
  for (int j = 0; j < 16; ++j) tmp[j] = t[c0+j][r];
  uint4* dp = (uint4*)&d[(size_t)(nt+r)*Ms + mt + c0];
  dp[0] = ((const uint4*)tmp)[0];
  dp[1] = ((const uint4*)tmp)[1];
}

// ============================================================
// Convert K,V (f32 in qkv) to hi/lo bf16; V transposed. (R4 proven)
// ============================================================
__global__ __launch_bounds__(256) void convert_kv(const float* __restrict__ qkv,
    __bf16* __restrict__ khi, __bf16* __restrict__ klo,
    __bf16* __restrict__ vthi, __bf16* __restrict__ vtlo)
{
  int t0 = blockIdx.x*64;
  int bh = blockIdx.y;
  int b = bh >> 3, h = bh & 7;
  int tid = threadIdx.x;
  {
    int r = tid >> 2, e0 = (tid & 3) * 16;
    const float* src = qkv + ((size_t)(b*TSEQ + t0 + r))*1536 + 512 + h*64 + e0;
    __bf16 hi[16] __attribute__((aligned(16)));
    __bf16 lo[16] __attribute__((aligned(16)));
    #pragma unroll
    for (int j = 0; j < 16; j += 4){
      float4 v = *(const float4*)(src + j);
      float f[4] = {v.x, v.y, v.z, v.w};
      #pragma unroll
      for (int q = 0; q < 4; ++q){
        __bf16 hb = (__bf16)f[q];
        hi[j+q] = hb; lo[j+q] = (__bf16)(f[q] - (float)hb);
      }
    }
    size_t off = ((size_t)(bh*TSEQ + t0 + r))*64 + e0;
    *(uint4*)(khi + off)     = ((const uint4*)hi)[0];
    *(uint4*)(khi + off + 8) = ((const uint4*)hi)[1];
    *(uint4*)(klo + off)     = ((const uint4*)lo)[0];
    *(uint4*)(klo + off + 8) = ((const uint4*)lo)[1];
  }
  {
    int key0 = (tid & 15) * 4, e0 = (tid >> 4) * 4;
    float4 v[4];
    #pragma unroll
    for (int j = 0; j < 4; ++j)
      v[j] = *(const float4*)(qkv + ((size_t)(b*TSEQ + t0 + key0 + j))*1536 + 1024 + h*64 + e0);
    float col[4][4];
    col[0][0]=v[0].x; col[0][1]=v[1].x; col[0][2]=v[2].x; col[0][3]=v[3].x;
    col[1][0]=v[0].y; col[1][1]=v[1].y; col[1][2]=v[2].y; col[1][3]=v[3].y;
    col[2][0]=v[0].z; col[2][1]=v[1].z; col[2][2]=v[2].z; col[2][3]=v[3].z;
    col[3][0]=v[0].w; col[3][1]=v[1].w; col[3][2]=v[2].w; col[3][3]=v[3].w;
    #pragma unroll
    for (int kk = 0; kk < 4; ++kk){
      __bf16 hi[4] __attribute__((aligned(8)));
      __bf16 lo[4] __attribute__((aligned(8)));
      #pragma unroll
      for (int j = 0; j < 4; ++j){
        __bf16 hb = (__bf16)col[kk][j];
        hi[j] = hb; lo[j] = (__bf16)(col[kk][j] - (float)hb);
      }
      size_t off = ((size_t)(bh*64 + e0 + kk))*TSEQ + t0 + key0;
      *(uint2*)(vthi + off) = *(const uint2*)hi;
      *(uint2*)(vtlo + off) = *(const uint2*)lo;
    }
  }
}

// ============================================================
// bf16x3 MFMA flash attention (causal), transposed compute.
// Shuffle-free PV (K=16 MFMA); counted-vmcnt prefetch pipeline.
// ============================================================
__global__ __launch_bounds__(512) void attn_mfma(const float* __restrict__ qkv,
    const __bf16* __restrict__ khi_g, const __bf16* __restrict__ klo_g,
    const __bf16* __restrict__ vthi_g, const __bf16* __restrict__ vtlo_g,
    __bf16* __restrict__ ahi, __bf16* __restrict__ alo)
{
  __shared__ __align__(16) char ldsbuf[65536];   // [2 buf][4 arr][8KB]
  int bh = blockIdx.x;
  int qtA = blockIdx.y, qtB = 15 - qtA;
  int b = bh >> 3, h = bh & 7;
  int tid = threadIdx.x;
  int w = tid >> 6, l = tid & 63;
  int g = l >> 4, r = l & 15;
  const float qsc = 0.04419417382415922f * 1.4426950408889634f;  // D^-0.5 * log2(e)

  int qb[2]; qb[0] = qtA*128 + w*16; qb[1] = qtB*128 + (7-w)*16;
  int kdiag[2]; kdiag[0] = qb[0] >> 6; kdiag[1] = qb[1] >> 6;

  bf16x8 qhi[2][2], qlo[2][2];
  #pragma unroll
  for (int qf = 0; qf < 2; ++qf)
    #pragma unroll
    for (int ks = 0; ks < 2; ++ks){
      const float* src = qkv + ((size_t)(b*TSEQ + qb[qf] + r))*1536 + h*64 + ks*32 + g*8;
      float4 v0 = *(const float4*)src;
      float4 v1 = *(const float4*)(src + 4);
      float f[8] = {v0.x,v0.y,v0.z,v0.w,v1.x,v1.y,v1.z,v1.w};
      bf16x8 hi, lo;
      #pragma unroll
      for (int i = 0; i < 8; ++i){
        float fs = f[i] * qsc;
        __bf16 hb = (__bf16)fs;
        hi[i] = hb; lo[i] = (__bf16)(fs - (float)hb);
      }
      qhi[qf][ks] = hi; qlo[qf][ks] = lo;
    }

  f32x4 ot[4][2] = {};
  float m_r[2] = {-INFINITY, -INFINITY};
  float l_r[2] = {0.f, 0.f};

  int nkt = 2*qtB + 2;
  size_t kbase = (size_t)bh*TSEQ*64;
  size_t vbase = (size_t)bh*64*TSEQ;

  auto STAGE = [&](int buf, int kt){
    int row = tid >> 3, cc = tid & 7;
    int sw = (cc ^ (row & 7)) * 8;
    char* d = ldsbuf + buf*32768 + (w << 10);
    gload16(khi_g  + kbase + (size_t)(kt*64 + row)*64 + sw, d);
    gload16(klo_g  + kbase + (size_t)(kt*64 + row)*64 + sw, d + 8192);
    gload16(vthi_g + vbase + (size_t)row*TSEQ + kt*64 + sw,  d + 16384);
    gload16(vtlo_g + vbase + (size_t)row*TSEQ + kt*64 + sw,  d + 24576);
  };

  STAGE(0, 0);

  for (int kt = 0; kt < nkt; ++kt){
    int buf = kt & 1;
    if (kt + 1 < nkt){ STAGE(buf ^ 1, kt + 1); WAITVM(4); }
    else             { WAITVM(0); }
    __builtin_amdgcn_s_barrier();

    bool act[2];
    act[0] = (kt <= kdiag[0]);
    act[1] = (kt <= kdiag[1]);

    const char* K0 = ldsbuf + buf*32768;
    const char* K1 = K0 + 8192;
    const char* V0 = K0 + 16384;
    const char* V1 = K0 + 24576;

    // ---- S^T = K · Q^T (bf16x3) ----
    f32x4 s[4][2] = {};
    #pragma unroll
    for (int kf = 0; kf < 4; ++kf){
      int rowk = kf*16 + r;
      int rsw = (rowk & 7) << 4;
      #pragma unroll
      for (int ks = 0; ks < 2; ++ks){
        int off = rowk*128 + ((((ks*4 + g) << 4)) ^ rsw);
        bf16x8 khf = *(const bf16x8*)(K0 + off);
        bf16x8 klf = *(const bf16x8*)(K1 + off);
        #pragma unroll
        for (int qf = 0; qf < 2; ++qf){
          if (act[qf]){
            s[kf][qf] = __builtin_amdgcn_mfma_f32_16x16x32_bf16(khf, qlo[qf][ks], s[kf][qf], 0,0,0);
            s[kf][qf] = __builtin_amdgcn_mfma_f32_16x16x32_bf16(klf, qhi[qf][ks], s[kf][qf], 0,0,0);
            s[kf][qf] = __builtin_amdgcn_mfma_f32_16x16x32_bf16(khf, qhi[qf][ks], s[kf][qf], 0,0,0);
          }
        }
      }
    }

    // ---- mask (diag tile only) + online softmax (exp2, defer-max) ----
    u32 phi[4][2][2], plo[4][2][2];
    #pragma unroll
    for (int qf = 0; qf < 2; ++qf){
      if (act[qf]){
        int q = qb[qf] + r;
        float p[4][4];
        float mx = -INFINITY;
        if (kt == kdiag[qf]){
          #pragma unroll
          for (int kf = 0; kf < 4; ++kf)
            #pragma unroll
            for (int e = 0; e < 4; ++e){
              int key = kt*64 + kf*16 + g*4 + e;
              float sv = (key <= q) ? s[kf][qf][e] : -INFINITY;
              p[kf][e] = sv;
              mx = fmaxf(mx, sv);
            }
        } else {
          #pragma unroll
          for (int kf = 0; kf < 4; ++kf)
            #pragma unroll
            for (int e = 0; e < 4; ++e){
              float sv = s[kf][qf][e];
              p[kf][e] = sv;
              mx = fmaxf(mx, sv);
            }
        }
        mx = fmaxf(mx, __shfl_xor(mx, 16));
        mx = fmaxf(mx, __shfl_xor(mx, 32));
        if (__any(mx > m_r[qf])){
          float mn = fmaxf(m_r[qf], mx);
          float fj = exp2f(m_r[qf] - mn);
          m_r[qf] = mn;
          l_r[qf] *= fj;
          #pragma unroll
          for (int ef = 0; ef < 4; ++ef)
            #pragma unroll
            for (int e = 0; e < 4; ++e)
              ot[ef][qf][e] *= fj;
        }
        float ts = 0.f;
        #pragma unroll
        for (int kf = 0; kf < 4; ++kf)
          #pragma unroll
          for (int e = 0; e < 4; ++e){
            float pv = exp2f(p[kf][e] - m_r[qf]);
            p[kf][e] = pv; ts += pv;
          }
        ts += __shfl_xor(ts, 16); ts += __shfl_xor(ts, 32);
        l_r[qf] += ts;
        #pragma unroll
        for (int kf = 0; kf < 4; ++kf){
          __bf16 h0=(__bf16)p[kf][0], h1=(__bf16)p[kf][1], h2=(__bf16)p[kf][2], h3=(__bf16)p[kf][3];
          phi[kf][qf][0] = pkbf(p[kf][0], p[kf][1]);
          phi[kf][qf][1] = pkbf(p[kf][2], p[kf][3]);
          plo[kf][qf][0] = pkbf(p[kf][0]-(float)h0, p[kf][1]-(float)h1);
          plo[kf][qf][1] = pkbf(p[kf][2]-(float)h2, p[kf][3]-(float)h3);
        }
      }
    }

    // ---- O^T += V^T · P^T via K=16 MFMA; P frags direct from registers ----
    #pragma unroll
    for (int kf = 0; kf < 4; ++kf){
      #pragma unroll
      for (int ef = 0; ef < 4; ++ef){
        int rowv = ef*16 + r;
        int off = rowv*128 + ((((2*kf + (g>>1)) ^ (rowv & 7)) << 4)) + (g&1)*8;
        s16x4 vh = *(const s16x4*)(V0 + off);
        s16x4 vl = *(const s16x4*)(V1 + off);
        #pragma unroll
        for (int qf = 0; qf < 2; ++qf){
          if (act[qf]){
            s16x4 ph = mk4(phi[kf][qf][0], phi[kf][qf][1]);
            s16x4 pl = mk4(plo[kf][qf][0], plo[kf][qf][1]);
            ot[ef][qf] = __builtin_amdgcn_mfma_f32_16x16x16bf16_1k(vh, pl, ot[ef][qf], 0,0,0);
            ot[ef][qf] = __builtin_amdgcn_mfma_f32_16x16x16bf16_1k(vl, ph, ot[ef][qf], 0,0,0);
            ot[ef][qf] = __builtin_amdgcn_mfma_f32_16x16x16bf16_1k(vh, ph, ot[ef][qf], 0,0,0);
          }
        }
      }
    }
    __builtin_amdgcn_s_barrier();
  }

  float* Osh = (float*)ldsbuf;   // [128][68]
  #pragma unroll
  for (int qf = 0; qf < 2; ++qf){
    float inv = 1.0f / l_r[qf];
    int qloc = (qf ? (7-w) : w)*16 + r;
    #pragma unroll
    for (int ef = 0; ef < 4; ++ef)
      #pragma unroll
      for (int e = 0; e < 4; ++e)
        Osh[qloc*68 + ef*16 + g*4 + e] = ot[ef][qf][e] * inv;
    __syncthreads();
    {
      int qt = qf ? qtB : qtA;
      int q = tid >> 2, e0 = (tid & 3)*16;
      const float* srow = Osh + q*68 + e0;
      size_t base = ((size_t)(b*TSEQ + qt*128 + q))*DD + h*64 + e0;
      #pragma unroll
      for (int j = 0; j < 4; ++j){
        float4 v = *(const float4*)(srow + j*4);
        float f[4] = {v.x, v.y, v.z, v.w};
        __bf16 hb[4] __attribute__((aligned(8)));
        __bf16 lb[4] __attribute__((aligned(8)));
        #pragma unroll
        for (int q2 = 0; q2 < 4; ++q2){
          __bf16 h2b = (__bf16)f[q2];
          hb[q2] = h2b; lb[q2] = (__bf16)(f[q2] - (float)h2b);
        }
        *(uint2*)(ahi + base + j*4) = *(const uint2*)hb;
        *(uint2*)(alo + base + j*4) = *(const uint2*)lb;
      }
    }
    __syncthreads();
  }
}

// ============================================================
// Fused LN2 + Router: reads x1, writes h2 (bf16) + routing
// ============================================================
__global__ __launch_bounds__(256) void routerln_kernel(const float* __restrict__ x1,
    const float* __restrict__ gw, const float* __restrict__ bw,
    const float* __restrict__ Wg, const float* __restrict__ bg,
    const float* __restrict__ Wn, const float* __restrict__ bn,
    __bf16* __restrict__ h2b,
    int* __restrict__ idx0, int* __restrict__ idx1,
    float* __restrict__ g0, float* __restrict__ g1)
{
  int wid = threadIdx.x >> 6, lane = threadIdx.x & 63;
  int tok = blockIdx.x*4 + wid;
  const float* xr = x1 + (size_t)tok*DD;
  float4 a = *(const float4*)(xr + lane*4);
  float4 c = *(const float4*)(xr + 256 + lane*4);
  float s  = a.x+a.y+a.z+a.w + c.x+c.y+c.z+c.w;
  float ss = a.x*a.x+a.y*a.y+a.z*a.z+a.w*a.w + c.x*c.x+c.y*c.y+c.z*c.z+c.w*c.w;
  #pragma unroll
  for (int off = 32; off; off >>= 1){ s += __shfl_xor(s, off); ss += __shfl_xor(ss, off); }
  float m   = s * (1.0f/DD);
  float var = ss * (1.0f/DD) - m*m;
  float rr  = 1.0f / sqrtf(var + 1e-5f);
  float4 g1v = *(const float4*)(gw + lane*4);
  float4 b1v = *(const float4*)(bw + lane*4);
  float4 g2v = *(const float4*)(gw + 256 + lane*4);
  float4 b2v = *(const float4*)(bw + 256 + lane*4);
  float f1[4], f2[4];
  f1[0]=(a.x-m)*rr*g1v.x+b1v.x; f1[1]=(a.y-m)*rr*g1v.y+b1v.y; f1[2]=(a.z-m)*rr*g1v.z+b1v.z; f1[3]=(a.w-m)*rr*g1v.w+b1v.w;
  f2[0]=(c.x-m)*rr*g2v.x+b2v.x; f2[1]=(c.y-m)*rr*g2v.y+b2v.y; f2[2]=(c.z-m)*rr*g2v.z+b2v.z; f2[3]=(c.w-m)*rr*g2v.w+b2v.w;
  {
    __bf16 h1v[4] __attribute__((aligned(8)));
    __bf16 h2v[4] __attribute__((aligned(8)));
    #pragma unroll
    for (int j = 0; j < 4; ++j){ h1v[j] = (__bf16)f1[j]; h2v[j] = (__bf16)f2[j]; }
    size_t base = (size_t)tok*DD + lane*4;
    *(uint2*)(h2b + base)       = *(const uint2*)h1v;
    *(uint2*)(h2b + base + 256) = *(const uint2*)h2v;
  }
  float ag[8] = {0,0,0,0,0,0,0,0}, an[8] = {0,0,0,0,0,0,0,0};
  int d1 = lane*4, d2 = 256 + lane*4;
  #pragma unroll
  for (int j = 0; j < 4; ++j){
    const float* wg1 = Wg + (size_t)(d1+j)*8;
    const float* wn1 = Wn + (size_t)(d1+j)*8;
    const float* wg2 = Wg + (size_t)(d2+j)*8;
    const float* wn2 = Wn + (size_t)(d2+j)*8;
    #pragma unroll
    for (int e = 0; e < 8; ++e){
      ag[e] = fmaf(f1[j], wg1[e], ag[e]); an[e] = fmaf(f1[j], wn1[e], an[e]);
      ag[e] = fmaf(f2[j], wg2[e], ag[e]); an[e] = fmaf(f2[j], wn2[e], an[e]);
    }
  }
  #pragma unroll
  for (int off = 32; off; off >>= 1){
    #pragma unroll
    for (int e = 0; e < 8; ++e){ ag[e] += __shfl_xor(ag[e], off); an[e] += __shfl_xor(an[e], off); }
  }
  __shared__ float ns[4][8];
  if (lane < 8){
    int e = lane;
    float lg = ag[e] + bg[e];
    float nl = an[e] + bn[e];
    float sp = fmaxf(nl, 0.f) + log1pf(expf(-fabsf(nl)));
    unsigned i = (unsigned)(tok*8 + e);
    unsigned r0b, r1b;
    threefry2x32(0u, i, r0b, r1b);
    unsigned bits = r0b ^ r1b;
    float f = __uint_as_float((bits >> 9) | 0x3f800000u) - 1.0f;
    float u = fmaf(f, 2.0f, -0.99999994f);
    u = fmaxf(u, -0.99999994f);
    float z = 1.41421356f * erfinv_f(u);
    ns[wid][e] = lg + z*sp;
  }
  __syncthreads();
  if (lane == 0){
    float v0 = -INFINITY; int i0 = 0;
    #pragma unroll
    for (int e = 0; e < 8; ++e){ float v = ns[wid][e]; if (v > v0){ v0 = v; i0 = e; } }
    float v1 = -INFINITY; int i1 = 0;
    #pragma unroll
    for (int e = 0; e < 8; ++e){ if (e != i0){ float v = ns[wid][e]; if (v > v1){ v1 = v; i1 = e; } } }
    float dexp = expf(v1 - v0);
    float ssum = 1.0f + dexp;
    idx0[tok] = i0; idx1[tok] = i1;
    g0[tok] = 1.0f/ssum; g1[tok] = dexp/ssum;
  }
}

// ============================================================
// Capacity routing
// ============================================================
__global__ __launch_bounds__(256) void route_scan(const int* __restrict__ idx0,
    const int* __restrict__ idx1, int* __restrict__ idx_buf, int* __restrict__ tok_slot)
{
  int e = blockIdx.x, tid = threadIdx.x;
  for (int i = tid; i < CAPK; i += 256) idx_buf[e*CAPK + i] = 0;
  __syncthreads();
  int base = tid * 32;
  int cnt = 0;
  for (int j = 0; j < 32; ++j){ int t = base + j; cnt += (idx0[t]==e || idx1[t]==e) ? 1 : 0; }
  __shared__ int ps[256];
  ps[tid] = cnt; __syncthreads();
  for (int off = 1; off < 256; off <<= 1){
    int add = (tid >= off) ? ps[tid - off] : 0;
    __syncthreads();
    ps[tid] += add;
    __syncthreads();
  }
  int slot = ps[tid] - cnt;
  for (int j = 0; j < 32; ++j){
    int t = base + j;
    int k = (idx0[t]==e) ? 0 : ((idx1[t]==e) ? 1 : -1);
    if (k >= 0){
      if (slot < CAPK){ idx_buf[e*CAPK + slot] = t; tok_slot[t*2 + k] = slot; }
      else            { tok_slot[t*2 + k] = -1; }
      slot++;
    }
  }
}

// ============================================================
// Combine (eout bf16)
// ============================================================
__global__ __launch_bounds__(128) void combine_kernel(const float* __restrict__ x1,
    const __bf16* __restrict__ eout, const int* __restrict__ idx0, const int* __restrict__ idx1,
    const float* __restrict__ g0, const float* __restrict__ g1,
    const int* __restrict__ tok_slot, float* __restrict__ outp)
{
  int n = blockIdx.x, t = threadIdx.x;
  float4 acc = *(const float4*)(x1 + (size_t)n*DD + t*4);
  #pragma unroll
  for (int k = 0; k < 2; ++k){
    int s = tok_slot[n*2 + k];
    if (s >= 0){
      int e  = (k==0) ? idx0[n] : idx1[n];
      float g = (k==0) ? g0[n] : g1[n];
      __bf16 vb[4] __attribute__((aligned(8)));
      *(uint2*)vb = *(const uint2*)(eout + ((size_t)(e*CAPK + s))*DD + t*4);
      acc.x = fmaf(g, (float)vb[0], acc.x); acc.y = fmaf(g, (float)vb[1], acc.y);
      acc.z = fmaf(g, (float)vb[2], acc.z); acc.w = fmaf(g, (float)vb[3], acc.w);
    }
  }
  *(float4*)(outp + (size_t)n*DD + t*4) = acc;
}

// ============================================================
extern "C" void kernel_launch(void* const* d_in, const int* in_sizes, int n_in,
                              void* d_out, int out_size, void* d_ws, size_t ws_size,
                              hipStream_t stream)
{
  const float* x    = (const float*)d_in[0];
  const float* ln1g = (const float*)d_in[1];
  const float* ln1b = (const float*)d_in[2];
  const float* Wq   = (const float*)d_in[3];
  const float* Wk   = (const float*)d_in[4];
  const float* Wv   = (const float*)d_in[5];
  const float* Wo   = (const float*)d_in[6];
  const float* bo   = (const float*)d_in[7];
  const float* ln2g = (const float*)d_in[8];
  const float* ln2b = (const float*)d_in[9];
  const float* Wg   = (const float*)d_in[10];
  const float* bg   = (const float*)d_in[11];
  const float* Wn   = (const float*)d_in[12];
  const float* bn   = (const float*)d_in[13];
  const float* W1   = (const float*)d_in[14];
  const float* b1   = (const float*)d_in[15];
  const float* W2   = (const float*)d_in[16];
  const float* b2   = (const float*)d_in[17];
  float* out = (float*)d_out;
  char* ws = (char*)d_ws;
  const size_t MB = 1u << 20;

  // workspace layout (time-aliased; peak ~145.5 MiB)
  __bf16* h1hi   = (__bf16*)(ws);             // 0..8   : LN1 hi (s1-3)
  __bf16* h1lo   = (__bf16*)(ws + 8*MB);      // 8..16  : LN1 lo
  __bf16* attnhi = (__bf16*)(ws);             // 0..8   : attn out hi (s4b-5)
  __bf16* attnlo = (__bf16*)(ws + 8*MB);      // 8..16
  __bf16* h2b    = (__bf16*)(ws);             // 0..8   : LN2 out bf16 (s6-10)
  float*  qkv    = (float*)(ws + 16*MB);      // 16..64 : qkv f32 (s3-4b)
  __bf16* W1T    = (__bf16*)(ws + 16*MB);     // 16..32 : (s7-10)
  __bf16* W2T    = (__bf16*)(ws + 32*MB);     // 32..48 : (s7-10)
  __bf16* eoutb  = (__bf16*)(ws + 48*MB);     // 48..64 : expert out bf16 (s10-11)
  float*  x1     = (float*)(ws + 64*MB);      // 64..80 : (s5-11)
  __bf16* Khi    = (__bf16*)(ws + 80*MB);     // 80..88 : (s4a-4b)
  __bf16* Klo    = (__bf16*)(ws + 88*MB);     // 88..96
  __bf16* Vthi   = (__bf16*)(ws + 96*MB);     // 96..104
  __bf16* Vtlo   = (__bf16*)(ws + 104*MB);    // 104..112
  __bf16* Bqh    = (__bf16*)(ws + 80*MB);     // 80..81.5 : qkv W hi (s2-3; dead before s4a)
  __bf16* Bql    = (__bf16*)(ws + 82*MB);     // 82..83.5
  __bf16* mid    = (__bf16*)(ws + 80*MB);     // 80..144 : all-8-expert mid (s10; over K/V, dead)
  __bf16* WoTh   = (__bf16*)(ws + 144*MB);    // 144..144.5 (s2-5)
  __bf16* WoTl   = (__bf16*)(ws + 144*MB + 512*1024);
  char*   smallp = ws + 145*MB;
  int*   idx0     = (int*)smallp;
  int*   idx1     = idx0 + NTOK;
  float* g0       = (float*)(idx1 + NTOK);
  float* g1       = g0 + NTOK;
  int*   tok_slot = (int*)(g1 + NTOK);
  int*   idx_buf  = tok_slot + NTOK*2;

  // 1. LN1 -> hi/lo bf16
  ln_split<<<dim3(NTOK/4), dim3(64,4), 0, stream>>>(x, ln1g, ln1b, h1hi, h1lo);
  // 2. weight packing/transposes
  pack_qkv_split<<<dim3(8,24), 256, 0, stream>>>(Wq, Wk, Wv, Bqh, Bql);
  transp_split<<<dim3(8,8), 256, 0, stream>>>(Wo, WoTh, WoTl, DD, DD);
  // 3. QKV projection (bf16x3 MFMA)
  gemm_mfma3<0,0><<<dim3(12,64), 256, 0, stream>>>(h1hi, h1lo, Bqh, Bql, nullptr, nullptr, qkv, NTOK, 1536, DD);
  // 4a. convert K,V -> hi/lo bf16 (V transposed)
  convert_kv<<<dim3(TSEQ/64, 32), 256, 0, stream>>>(qkv, Khi, Klo, Vthi, Vtlo);
  // 4b. causal flash attention (shuffle-free PV, counted-vmcnt)
  attn_mfma<<<dim3(32, 8), 512, 0, stream>>>(qkv, Khi, Klo, Vthi, Vtlo, attnhi, attnlo);
  // 5. Wo projection + bias + residual -> x1
  gemm_mfma3<1,1><<<dim3(4,64), 256, 0, stream>>>(attnhi, attnlo, WoTh, WoTl, bo, x, x1, NTOK, DD, DD);
  // 6. fused LN2 + router
  routerln_kernel<<<dim3(NTOK/4), 256, 0, stream>>>(x1, ln2g, ln2b, Wg, bg, Wn, bn,
      h2b, idx0, idx1, g0, g1);
  // 7. expert weights -> bf16 transposed
  transp_conv<<<dim3(32,8,NE), 256, 0, stream>>>(W1, W1T, DD, FF);
  transp_conv<<<dim3(8,32,NE), 256, 0, stream>>>(W2, W2T, FF, DD);
  // 8. capacity scan
  route_scan<<<dim3(NE), 256, 0, stream>>>(idx0, idx1, idx_buf, tok_slot);
  // 9+10. expert FFN, all 8 experts per launch (e = flat&7 -> one per XCD);
  //       W1 gathers tokens directly via idx_buf
  gemm_mfma<1,1,1,4,3><<<dim3(8*16*16), 256, 0, stream>>>(
      h2b, W1T, b1, mid, idx_buf, CAPK, FF, DD);
  gemm_mfma<1,0,0,2,3><<<dim3(8*16*4), 256, 0, stream>>>(
      mid, W2T, b2, eoutb, nullptr, CAPK, DD, FF);
  // 11. combine + residual
  combine_kernel<<<dim3(NTOK), 128, 0, stream>>>(x1, eoutb, idx0, idx1, g0, g1, tok_slot, out);
}

// Round 10
// 367.084 us; speedup vs baseline: 1.0512x; 1.0512x over previous
//
#include <hip/hip_runtime.h>
#include <math.h>

// ---------------- problem constants ----------------
#define TSEQ 2048
#define DD   512
#define NH   8
#define HSZ  64
#define NE   8
#define NTOK 8192    // B*T
#define CAPK 2048
#define FF   2048    // 4*D

typedef __bf16 bf16x8 __attribute__((ext_vector_type(8)));
typedef float  f32x4  __attribute__((ext_vector_type(4)));
typedef unsigned int u32;
typedef u32 u32x2 __attribute__((ext_vector_type(2)));
typedef short s16x4 __attribute__((ext_vector_type(4)));

// counted vector-memory wait (T4)
#define WAITVM(N) asm volatile("s_waitcnt vmcnt(" #N ")" ::: "memory")

__device__ __forceinline__ void gload16(const void* g, void* l){
  __builtin_amdgcn_global_load_lds((const __attribute__((address_space(1))) u32*)g,
                                   (__attribute__((address_space(3))) u32*)l, 16, 0, 0);
}

__device__ __forceinline__ u32 pkbf(float a, float b){
  unsigned short ua = __builtin_bit_cast(unsigned short, (__bf16)a);
  unsigned short ub = __builtin_bit_cast(unsigned short, (__bf16)b);
  return (u32)ua | ((u32)ub << 16);
}

__device__ __forceinline__ s16x4 mk4(u32 a, u32 b){
  u32x2 t; t[0] = a; t[1] = b;
  return __builtin_bit_cast(s16x4, t);
}

// ============================================================
// Threefry-2x32, key = (0, 42)
// ============================================================
__device__ __forceinline__ unsigned rotl32(unsigned x, int r){ return (x<<r)|(x>>(32-r)); }

__device__ __forceinline__ void threefry2x32(unsigned c0, unsigned c1, unsigned &o0, unsigned &o1){
  const unsigned k0 = 0u, k1 = 42u;
  const unsigned k2 = k0 ^ k1 ^ 0x1BD11BDAu;
  unsigned x0 = c0 + k0, x1 = c1 + k1;
#define TFR(rot) { x0 += x1; x1 = rotl32(x1, rot); x1 ^= x0; }
  TFR(13) TFR(15) TFR(26) TFR(6)   x0 += k1; x1 += k2 + 1u;
  TFR(17) TFR(29) TFR(16) TFR(24)  x0 += k2; x1 += k0 + 2u;
  TFR(13) TFR(15) TFR(26) TFR(6)   x0 += k0; x1 += k1 + 3u;
  TFR(17) TFR(29) TFR(16) TFR(24)  x0 += k1; x1 += k2 + 4u;
  TFR(13) TFR(15) TFR(26) TFR(6)   x0 += k2; x1 += k0 + 5u;
#undef TFR
  o0 = x0; o1 = x1;
}

__device__ __forceinline__ float erfinv_f(float x){
  float w = -log1pf(-x*x);
  float p;
  if (w < 5.0f){
    w -= 2.5f;
    p = 2.81022636e-08f;
    p = fmaf(p,w, 3.43273939e-07f);
    p = fmaf(p,w,-3.5233877e-06f);
    p = fmaf(p,w,-4.39150654e-06f);
    p = fmaf(p,w, 0.00021858087f);
    p = fmaf(p,w,-0.00125372503f);
    p = fmaf(p,w,-0.00417768164f);
    p = fmaf(p,w, 0.246640727f);
    p = fmaf(p,w, 1.50140941f);
  } else {
    w = sqrtf(w) - 3.0f;
    p = -0.000200214257f;
    p = fmaf(p,w, 0.000100950558f);
    p = fmaf(p,w, 0.00134934322f);
    p = fmaf(p,w,-0.00367342844f);
    p = fmaf(p,w, 0.00573950773f);
    p = fmaf(p,w,-0.0076224613f);
    p = fmaf(p,w, 0.00943887047f);
    p = fmaf(p,w, 1.00167406f);
    p = fmaf(p,w, 2.83297682f);
  }
  return p * x;
}

// ============================================================
// Merged prep: LN1->hi/lo bf16 (blk<2048), pack QKV W (2048..2239),
// transpose+split Wo (2240..2303)
// ============================================================
__global__ __launch_bounds__(256) void prep_kernel(
    const float* __restrict__ x, const float* __restrict__ ln1g, const float* __restrict__ ln1b,
    __bf16* __restrict__ h1hi, __bf16* __restrict__ h1lo,
    const float* __restrict__ Wq, const float* __restrict__ Wk, const float* __restrict__ Wv,
    __bf16* __restrict__ Bqh, __bf16* __restrict__ Bql,
    const float* __restrict__ Wo, __bf16* __restrict__ WoTh, __bf16* __restrict__ WoTl)
{
  __shared__ float t[64][65];
  int blk = blockIdx.x;
  int tid = threadIdx.x;
  if (blk < 2048){
    int row  = blk*4 + (tid >> 6);
    int lane = tid & 63;
    const float* xr = x + (size_t)row*DD;
    float4 a = *(const float4*)(xr + lane*4);
    float4 c = *(const float4*)(xr + 256 + lane*4);
    float s  = a.x+a.y+a.z+a.w + c.x+c.y+c.z+c.w;
    float ss = a.x*a.x+a.y*a.y+a.z*a.z+a.w*a.w + c.x*c.x+c.y*c.y+c.z*c.z+c.w*c.w;
    #pragma unroll
    for (int off = 32; off; off >>= 1){ s += __shfl_xor(s, off); ss += __shfl_xor(ss, off); }
    float m   = s * (1.0f/DD);
    float var = ss * (1.0f/DD) - m*m;
    float r   = 1.0f / sqrtf(var + 1e-5f);
    float4 g1 = *(const float4*)(ln1g + lane*4);
    float4 b1 = *(const float4*)(ln1b + lane*4);
    float4 g2 = *(const float4*)(ln1g + 256 + lane*4);
    float4 b2 = *(const float4*)(ln1b + 256 + lane*4);
    float f1[4], f2[4];
    f1[0]=(a.x-m)*r*g1.x+b1.x; f1[1]=(a.y-m)*r*g1.y+b1.y; f1[2]=(a.z-m)*r*g1.z+b1.z; f1[3]=(a.w-m)*r*g1.w+b1.w;
    f2[0]=(c.x-m)*r*g2.x+b2.x; f2[1]=(c.y-m)*r*g2.y+b2.y; f2[2]=(c.z-m)*r*g2.z+b2.z; f2[3]=(c.w-m)*r*g2.w+b2.w;
    __bf16 h1v[4] __attribute__((aligned(8))), l1v[4] __attribute__((aligned(8)));
    __bf16 h2v[4] __attribute__((aligned(8))), l2v[4] __attribute__((aligned(8)));
    #pragma unroll
    for (int j = 0; j < 4; ++j){
      __bf16 hb = (__bf16)f1[j]; h1v[j]=hb; l1v[j]=(__bf16)(f1[j]-(float)hb);
      __bf16 hc = (__bf16)f2[j]; h2v[j]=hc; l2v[j]=(__bf16)(f2[j]-(float)hc);
    }
    size_t base = (size_t)row*DD + lane*4;
    *(uint2*)(h1hi + base)       = *(const uint2*)h1v;
    *(uint2*)(h1lo + base)       = *(const uint2*)l1v;
    *(uint2*)(h1hi + base + 256) = *(const uint2*)h2v;
    *(uint2*)(h1lo + base + 256) = *(const uint2*)l2v;
  } else if (blk < 2240){
    int bx = blk - 2048;
    int kt = (bx & 7) * 64;
    int z  = bx >> 3;
    int sel = z >> 3, hh = z & 7;
    const float* W = (sel==0 ? Wq : (sel==1 ? Wk : Wv)) + (size_t)hh*DD*HSZ;
    int r = tid>>2, c0 = (tid&3)*16;
    #pragma unroll
    for (int j = 0; j < 16; j += 4){
      float4 v = *(const float4*)&W[(size_t)(kt+r)*HSZ + c0 + j];
      t[r][c0+j]=v.x; t[r][c0+j+1]=v.y; t[r][c0+j+2]=v.z; t[r][c0+j+3]=v.w;
    }
    __syncthreads();
    __bf16 hb[16] __attribute__((aligned(32)));
    __bf16 lb[16] __attribute__((aligned(32)));
    #pragma unroll
    for (int j = 0; j < 16; ++j){
      float f = t[c0+j][r];
      __bf16 h = (__bf16)f; hb[j]=h; lb[j]=(__bf16)(f-(float)h);
    }
    size_t off = (size_t)(z*64 + r)*512 + kt + c0;
    *(uint4*)(Bqh+off) = ((const uint4*)hb)[0]; *(uint4*)(Bqh+off+8) = ((const uint4*)hb)[1];
    *(uint4*)(Bql+off) = ((const uint4*)lb)[0]; *(uint4*)(Bql+off+8) = ((const uint4*)lb)[1];
  } else {
    int bx = blk - 2240;
    int nt = (bx & 7) * 64, mt = (bx >> 3) * 64;
    int r = tid>>2, c0 = (tid&3)*16;
    #pragma unroll
    for (int j = 0; j < 16; j += 4){
      float4 v = *(const float4*)&Wo[(size_t)(mt+r)*DD + nt + c0 + j];
      t[r][c0+j]=v.x; t[r][c0+j+1]=v.y; t[r][c0+j+2]=v.z; t[r][c0+j+3]=v.w;
    }
    __syncthreads();
    __bf16 hb[16] __attribute__((aligned(32)));
    __bf16 lb[16] __attribute__((aligned(32)));
    #pragma unroll
    for (int j = 0; j < 16; ++j){
      float f = t[c0+j][r];
      __bf16 h = (__bf16)f; hb[j]=h; lb[j]=(__bf16)(f-(float)h);
    }
    size_t off = (size_t)(nt + r)*DD + mt + c0;
    *(uint4*)(WoTh+off) = ((const uint4*)hb)[0]; *(uint4*)(WoTh+off+8) = ((const uint4*)hb)[1];
    *(uint4*)(WoTl+off) = ((const uint4*)lb)[0]; *(uint4*)(WoTl+off+8) = ((const uint4*)lb)[1];
  }
}

// ============================================================
// bf16x3 split-precision MFMA GEMM, 2-phase, counted-vmcnt pipeline.
// ============================================================
template<int BIAS, int RES>
__global__ __launch_bounds__(256) void gemm_mfma3(
    const __bf16* __restrict__ Ahi, const __bf16* __restrict__ Alo,
    const __bf16* __restrict__ Bhi, const __bf16* __restrict__ Blo,
    const float* __restrict__ bias, const float* __restrict__ res,
    float* __restrict__ C, int M, int N, int K)
{
  __shared__ __bf16 AsH[2][4096];
  __shared__ __bf16 AsL[2][4096];
  __shared__ __bf16 BsH[2][4096];
  __shared__ __bf16 BsL[2][4096];
  int m0 = blockIdx.y*128, n0 = blockIdx.x*128;
  int tid = threadIdx.x;
  int w = tid>>6, l = tid&63;
  int wm = w>>1, wn = w&1;
  int srow = w*32 + (l>>2);
  int skb  = (l&3)<<4;
  const char* agh = (const char*)(Ahi + (size_t)(m0+srow)*K) + skb;
  const char* agl = (const char*)(Alo + (size_t)(m0+srow)*K) + skb;
  const char* bgh = (const char*)(Bhi + (size_t)(n0+srow)*K) + skb;
  const char* bgl = (const char*)(Blo + (size_t)(n0+srow)*K) + skb;
  size_t r16 = (size_t)16*K*sizeof(__bf16);

  f32x4 acc[4][4] = {};
  int rl = l & 15, kh = l >> 4;
  const __bf16* abh = &AsH[0][(wm*64 + rl)*32 + kh*8];
  const __bf16* abl = &AsL[0][(wm*64 + rl)*32 + kh*8];
  const __bf16* bbh = &BsH[0][(wn*64 + rl)*32 + kh*8];
  const __bf16* bbl = &BsL[0][(wn*64 + rl)*32 + kh*8];

  auto STAGE = [&](int bb, int kt){
    size_t o = (size_t)kt*64;
    gload16(agh+o,     &AsH[bb][w*1024]);
    gload16(agh+o+r16, &AsH[bb][w*1024+512]);
    gload16(agl+o,     &AsL[bb][w*1024]);
    gload16(agl+o+r16, &AsL[bb][w*1024+512]);
    gload16(bgh+o,     &BsH[bb][w*1024]);
    gload16(bgh+o+r16, &BsH[bb][w*1024+512]);
    gload16(bgl+o,     &BsL[bb][w*1024]);
    gload16(bgl+o+r16, &BsL[bb][w*1024+512]);
  };

  int nkt = K >> 5;
  STAGE(0, 0);
  for (int kt = 0; kt < nkt; ++kt){
    int bb = kt & 1;
    if (kt + 1 < nkt){ STAGE(bb^1, kt+1); WAITVM(8); }
    else             { WAITVM(0); }
    __builtin_amdgcn_s_barrier();
    bf16x8 afh[4], afl[4], bfh[4], bfl[4];
    #pragma unroll
    for (int i = 0; i < 4; ++i){
      afh[i] = *(const bf16x8*)(abh + bb*4096 + i*512);
      afl[i] = *(const bf16x8*)(abl + bb*4096 + i*512);
      bfh[i] = *(const bf16x8*)(bbh + bb*4096 + i*512);
      bfl[i] = *(const bf16x8*)(bbl + bb*4096 + i*512);
    }
    #pragma unroll
    for (int fm = 0; fm < 4; ++fm)
      #pragma unroll
      for (int fn = 0; fn < 4; ++fn){
        acc[fm][fn] = __builtin_amdgcn_mfma_f32_16x16x32_bf16(afh[fm], bfl[fn], acc[fm][fn], 0, 0, 0);
        acc[fm][fn] = __builtin_amdgcn_mfma_f32_16x16x32_bf16(afl[fm], bfh[fn], acc[fm][fn], 0, 0, 0);
        acc[fm][fn] = __builtin_amdgcn_mfma_f32_16x16x32_bf16(afh[fm], bfh[fn], acc[fm][fn], 0, 0, 0);
      }
    __builtin_amdgcn_s_barrier();
  }

  int ccol = l & 15, cr = (l >> 4) * 4;
  #pragma unroll
  for (int fn = 0; fn < 4; ++fn){
    int n = n0 + wn*64 + fn*16 + ccol;
    float bv = BIAS ? bias[n] : 0.0f;
    #pragma unroll
    for (int fm = 0; fm < 4; ++fm){
      int mb = m0 + wm*64 + fm*16 + cr;
      #pragma unroll
      for (int r = 0; r < 4; ++r){
        float v = acc[fm][fn][r] + bv;
        if (RES) v += res[(size_t)(mb+r)*N + n];
        C[(size_t)(mb+r)*N + n] = v;
      }
    }
  }
}

// ============================================================
// bf16 MFMA GEMM (experts), 2-phase counted-vmcnt, XCD-local experts.
// ============================================================
template<int STORE_BF16, int RELU, int GATHER, int LOGN, int EBITS>
__global__ __launch_bounds__(256) void gemm_mfma(
    const __bf16* __restrict__ A, const __bf16* __restrict__ Bt,
    const float* __restrict__ bias, void* __restrict__ Cv,
    const int* __restrict__ idxb, int M, int N, int K)
{
  __shared__ __bf16 Asl[2][4096];
  __shared__ __bf16 Bsl[2][4096];
  int flat = blockIdx.x;
  int e = flat & ((1<<EBITS)-1);
  int tile = flat >> EBITS;
  int n0 = (tile & ((1<<LOGN)-1)) * 128;
  int m0 = (tile >> LOGN) * 128;
  const __bf16* Be = Bt + (size_t)e*N*K;
  const float*  be = bias + (size_t)e*N;
  int tid = threadIdx.x;
  int w = tid>>6, l = tid&63;
  int wm = w>>1, wn = w&1;
  int srow = w*32 + (l>>2);
  int skb  = (l&3)<<4;
  const char* ag;
  if (GATHER){
    int tok = idxb[e*CAPK + m0 + srow];
    ag = (const char*)(A + (size_t)tok*K) + skb;
  } else {
    ag = (const char*)(A + (size_t)e*M*K + (size_t)(m0 + srow)*K) + skb;
  }
  const char* bg = (const char*)(Be + (size_t)(n0 + srow)*K) + skb;
  size_t r16;
  if (GATHER){
    int tok2 = idxb[e*CAPK + m0 + srow + 16];
    r16 = (size_t)((const char*)(A + (size_t)tok2*K) + skb - ag);
  } else {
    r16 = (size_t)16*K*sizeof(__bf16);
  }

  f32x4 acc[4][4] = {};
  int rl = l & 15, kh = l >> 4;
  const __bf16* abase = &Asl[0][(wm*64 + rl)*32 + kh*8];
  const __bf16* bbase = &Bsl[0][(wn*64 + rl)*32 + kh*8];

  size_t br16 = (size_t)16*K*sizeof(__bf16);
  auto STAGE = [&](int bb, int kt){
    size_t o = (size_t)kt*64;
    gload16(ag+o,      &Asl[bb][w*1024]);
    gload16(ag+o+r16,  &Asl[bb][w*1024+512]);
    gload16(bg+o,      &Bsl[bb][w*1024]);
    gload16(bg+o+br16, &Bsl[bb][w*1024+512]);
  };

  int nkt = K >> 5;
  STAGE(0, 0);
  for (int kt = 0; kt < nkt; ++kt){
    int bb = kt & 1;
    if (kt + 1 < nkt){ STAGE(bb^1, kt+1); WAITVM(4); }
    else             { WAITVM(0); }
    __builtin_amdgcn_s_barrier();
    bf16x8 af[4], bf[4];
    #pragma unroll
    for (int i = 0; i < 4; ++i){
      af[i] = *(const bf16x8*)(abase + bb*4096 + i*512);
      bf[i] = *(const bf16x8*)(bbase + bb*4096 + i*512);
    }
    #pragma unroll
    for (int fm = 0; fm < 4; ++fm)
      #pragma unroll
      for (int fn = 0; fn < 4; ++fn)
        acc[fm][fn] = __builtin_amdgcn_mfma_f32_16x16x32_bf16(af[fm], bf[fn], acc[fm][fn], 0, 0, 0);
    __builtin_amdgcn_s_barrier();
  }

  int ccol = l & 15, cr = (l >> 4) * 4;
  char* Ce = (char*)Cv + (size_t)e*M*N*(STORE_BF16 ? 2 : 4);
  #pragma unroll
  for (int fn = 0; fn < 4; ++fn){
    int n = n0 + wn*64 + fn*16 + ccol;
    float bv = be[n];
    #pragma unroll
    for (int fm = 0; fm < 4; ++fm){
      int mb = m0 + wm*64 + fm*16 + cr;
      #pragma unroll
      for (int r = 0; r < 4; ++r){
        float v = acc[fm][fn][r] + bv;
        if (RELU) v = fmaxf(v, 0.f);
        if (STORE_BF16) ((__bf16*)Ce)[(size_t)(mb+r)*N + n] = (__bf16)v;
        else            ((float*)Ce)[(size_t)(mb+r)*N + n] = v;
      }
    }
  }
}

// ============================================================
// Merged transpose+convert W1,W2 (f32 -> plain bf16 [N][K])
// grid (512, 1, 8): id<256 -> W1 (DDxFF), else W2 (FFxDD)
// ============================================================
__global__ __launch_bounds__(256) void transp_conv2(const float* __restrict__ W1,
    const float* __restrict__ W2, __bf16* __restrict__ d1, __bf16* __restrict__ d2)
{
  __shared__ __bf16 t[64][72];
  int e = blockIdx.z;
  int id = blockIdx.x;
  const float* s; __bf16* d; int Ms, Ns, mt, nt;
  if (id < 256){ s = W1; d = d1; Ms = DD; Ns = FF; nt = (id&31)*64; mt = (id>>5)*64; }
  else { int i2 = id-256; s = W2; d = d2; Ms = FF; Ns = DD; nt = (i2&7)*64; mt = (i2>>3)*64; }
  s += (size_t)e*Ms*Ns;
  d += (size_t)e*Ms*Ns;
  int tid = threadIdx.x;
  int r = tid>>2, c0 = (tid&3)*16;
  #pragma unroll
  for (int j = 0; j < 16; j += 4){
    float4 v = *(const float4*)&s[(size_t)(mt+r)*Ns + nt + c0 + j];
    t[r][c0+j]   = (__bf16)v.x; t[r][c0+j+1] = (__bf16)v.y;
    t[r][c0+j+2] = (__bf16)v.z; t[r][c0+j+3] = (__bf16)v.w;
  }
  __syncthreads();
  __bf16 tmp[16] __attribute__((aligned(32)));
  #pragma unroll
  for (int j = 0; j < 16; ++j) tmp[j] = t[c0+j][r];
  uint4* dp = (uint4*)&d[(size_t)(nt+r)*Ms + mt + c0];
  dp[0] = ((const uint4*)tmp)[0];
  dp[1] = ((const uint4*)tmp)[1];
}

// ============================================================
// Convert K,V (f32 in qkv) to hi/lo bf16; V transposed.
// ============================================================
__global__ __launch_bounds__(256) void convert_kv(const float* __restrict__ qkv,
    __bf16* __restrict__ khi, __bf16* __restrict__ klo,
    __bf16* __restrict__ vthi, __bf16* __restrict__ vtlo)
{
  int t0 = blockIdx.x*64;
  int bh = blockIdx.y;
  int b = bh >> 3, h = bh & 7;
  int tid = threadIdx.x;
  {
    int r = tid >> 2, e0 = (tid & 3) * 16;
    const float* src = qkv + ((size_t)(b*TSEQ + t0 + r))*1536 + 512 + h*64 + e0;
    __bf16 hi[16] __attribute__((aligned(16)));
    __bf16 lo[16] __attribute__((aligned(16)));
    #pragma unroll
    for (int j = 0; j < 16; j += 4){
      float4 v = *(const float4*)(src + j);
      float f[4] = {v.x, v.y, v.z, v.w};
      #pragma unroll
      for (int q = 0; q < 4; ++q){
        __bf16 hb = (__bf16)f[q];
        hi[j+q] = hb; lo[j+q] = (__bf16)(f[q] - (float)hb);
      }
    }
    size_t off = ((size_t)(bh*TSEQ + t0 + r))*64 + e0;
    *(uint4*)(khi + off)     = ((const uint4*)hi)[0];
    *(uint4*)(khi + off + 8) = ((const uint4*)hi)[1];
    *(uint4*)(klo + off)     = ((const uint4*)lo)[0];
    *(uint4*)(klo + off + 8) = ((const uint4*)lo)[1];
  }
  {
    int key0 = (tid & 15) * 4, e0 = (tid >> 4) * 4;
    float4 v[4];
    #pragma unroll
    for (int j = 0; j < 4; ++j)
      v[j] = *(const float4*)(qkv + ((size_t)(b*TSEQ + t0 + key0 + j))*1536 + 1024 + h*64 + e0);
    float col[4][4];
    col[0][0]=v[0].x; col[0][1]=v[1].x; col[0][2]=v[2].x; col[0][3]=v[3].x;
    col[1][0]=v[0].y; col[1][1]=v[1].y; col[1][2]=v[2].y; col[1][3]=v[3].y;
    col[2][0]=v[0].z; col[2][1]=v[1].z; col[2][2]=v[2].z; col[2][3]=v[3].z;
    col[3][0]=v[0].w; col[3][1]=v[1].w; col[3][2]=v[2].w; col[3][3]=v[3].w;
    #pragma unroll
    for (int kk = 0; kk < 4; ++kk){
      __bf16 hi[4] __attribute__((aligned(8)));
      __bf16 lo[4] __attribute__((aligned(8)));
      #pragma unroll
      for (int j = 0; j < 4; ++j){
        __bf16 hb = (__bf16)col[kk][j];
        hi[j] = hb; lo[j] = (__bf16)(col[kk][j] - (float)hb);
      }
      size_t off = ((size_t)(bh*64 + e0 + kk))*TSEQ + t0 + key0;
      *(uint2*)(vthi + off) = *(const uint2*)hi;
      *(uint2*)(vtlo + off) = *(const uint2*)lo;
    }
  }
}

// ============================================================
// bf16x3 MFMA flash attention, KVBLK=128, dynamic LDS 128KB.
// Transposed compute; shuffle-free PV (K=16 MFMA); counted vmcnt(8).
// LDS per buf (64KB): [Khi 16K][Klo 16K][Vthi 16K][Vtlo 16K]
// K layout: key-row (0..127) x 128B (64 dims, 16B chunks swizzled by row&7)
// V layout: [pass=chunk>>3][dim-row 0..63]x128B (key chunks swizzled by row&7)
// ============================================================
__global__ __launch_bounds__(512) void attn_mfma(const float* __restrict__ qkv,
    const __bf16* __restrict__ khi_g, const __bf16* __restrict__ klo_g,
    const __bf16* __restrict__ vthi_g, const __bf16* __restrict__ vtlo_g,
    __bf16* __restrict__ ahi, __bf16* __restrict__ alo)
{
  extern __shared__ __align__(16) char ldsbuf[];
  int bh = blockIdx.x;
  int qtA = blockIdx.y, qtB = 15 - qtA;      // 128-row q-tiles
  int b = bh >> 3, h = bh & 7;
  int tid = threadIdx.x;
  int w = tid >> 6, l = tid & 63;
  int g = l >> 4, r = l & 15;
  const float qsc = 0.04419417382415922f * 1.4426950408889634f;  // D^-0.5 * log2(e)

  int qb[2]; qb[0] = qtA*128 + w*16; qb[1] = qtB*128 + (7-w)*16;
  int kdiag[2]; kdiag[0] = qtA; kdiag[1] = qtB;

  bf16x8 qhi[2][2], qlo[2][2];
  #pragma unroll
  for (int qf = 0; qf < 2; ++qf)
    #pragma unroll
    for (int ks = 0; ks < 2; ++ks){
      const float* src = qkv + ((size_t)(b*TSEQ + qb[qf] + r))*1536 + h*64 + ks*32 + g*8;
      float4 v0 = *(const float4*)src;
      float4 v1 = *(const float4*)(src + 4);
      float f[8] = {v0.x,v0.y,v0.z,v0.w,v1.x,v1.y,v1.z,v1.w};
      bf16x8 hi, lo;
      #pragma unroll
      for (int i = 0; i < 8; ++i){
        float fs = f[i] * qsc;
        __bf16 hb = (__bf16)fs;
        hi[i] = hb; lo[i] = (__bf16)(fs - (float)hb);
      }
      qhi[qf][ks] = hi; qlo[qf][ks] = lo;
    }

  f32x4 ot[4][2] = {};
  float m_r[2] = {-INFINITY, -INFINITY};
  float l_r[2] = {0.f, 0.f};

  int nkt = qtB + 1;
  size_t kbase = (size_t)bh*TSEQ*64;
  size_t vbase = (size_t)bh*64*TSEQ;

  // 8 gload16 per thread per 128-key tile
  auto STAGE = [&](int buf, int kt){
    int row = tid >> 3, cc = tid & 7;     // row 0..63, chunk-in-pass 0..7
    char* base = ldsbuf + buf*65536 + (w << 10);
    #pragma unroll
    for (int p = 0; p < 2; ++p){
      int krow = p*64 + row;
      int ksw = (cc ^ (krow & 7)) * 8;
      gload16(khi_g + kbase + (size_t)(kt*128 + krow)*64 + ksw, base + p*8192);
      gload16(klo_g + kbase + (size_t)(kt*128 + krow)*64 + ksw, base + 16384 + p*8192);
      int vch = p*8 + cc;
      int vsw = ((vch ^ (row & 7)) & 15) * 8;
      gload16(vthi_g + vbase + (size_t)row*TSEQ + kt*128 + vsw, base + 32768 + p*8192);
      gload16(vtlo_g + vbase + (size_t)row*TSEQ + kt*128 + vsw, base + 49152 + p*8192);
    }
  };

  STAGE(0, 0);

  for (int kt = 0; kt < nkt; ++kt){
    int buf = kt & 1;
    if (kt + 1 < nkt){ STAGE(buf ^ 1, kt + 1); WAITVM(8); }
    else             { WAITVM(0); }
    __builtin_amdgcn_s_barrier();

    bool act[2];
    act[0] = (kt <= kdiag[0]);
    act[1] = true;                         // kt <= qtB always

    const char* K0 = ldsbuf + buf*65536;
    const char* K1 = K0 + 16384;
    const char* V0 = K0 + 32768;
    const char* V1 = K0 + 49152;

    // ---- S^T = K · Q^T (bf16x3), 8 key-frags ----
    f32x4 s[8][2] = {};
    #pragma unroll
    for (int kf = 0; kf < 8; ++kf){
      int rowk = kf*16 + r;
      int rsw = (rowk & 7) << 4;
      #pragma unroll
      for (int ks = 0; ks < 2; ++ks){
        int off = rowk*128 + ((((ks*4 + g) << 4)) ^ rsw);
        bf16x8 khf = *(const bf16x8*)(K0 + off);
        bf16x8 klf = *(const bf16x8*)(K1 + off);
        #pragma unroll
        for (int qf = 0; qf < 2; ++qf){
          if (act[qf]){
            s[kf][qf] = __builtin_amdgcn_mfma_f32_16x16x32_bf16(khf, qlo[qf][ks], s[kf][qf], 0,0,0);
            s[kf][qf] = __builtin_amdgcn_mfma_f32_16x16x32_bf16(klf, qhi[qf][ks], s[kf][qf], 0,0,0);
            s[kf][qf] = __builtin_amdgcn_mfma_f32_16x16x32_bf16(khf, qhi[qf][ks], s[kf][qf], 0,0,0);
          }
        }
      }
    }

    // ---- mask (diag tile) + online softmax over 128 keys (exp2, defer-max) ----
    #pragma unroll
    for (int qf = 0; qf < 2; ++qf){
      if (act[qf]){
        int q = qb[qf] + r;
        float mx = -INFINITY;
        if (kt == kdiag[qf]){
          #pragma unroll
          for (int kf = 0; kf < 8; ++kf)
            #pragma unroll
            for (int e = 0; e < 4; ++e){
              int key = kt*128 + kf*16 + g*4 + e;
              float sv = (key <= q) ? s[kf][qf][e] : -INFINITY;
              s[kf][qf][e] = sv;
              mx = fmaxf(mx, sv);
            }
        } else {
          #pragma unroll
          for (int kf = 0; kf < 8; ++kf)
            #pragma unroll
            for (int e = 0; e < 4; ++e)
              mx = fmaxf(mx, s[kf][qf][e]);
        }
        mx = fmaxf(mx, __shfl_xor(mx, 16));
        mx = fmaxf(mx, __shfl_xor(mx, 32));
        if (__any(mx > m_r[qf])){
          float mn = fmaxf(m_r[qf], mx);
          float fj = exp2f(m_r[qf] - mn);
          m_r[qf] = mn;
          l_r[qf] *= fj;
          #pragma unroll
          for (int ef = 0; ef < 4; ++ef)
            #pragma unroll
            for (int e = 0; e < 4; ++e)
              ot[ef][qf][e] *= fj;
        }
        float ts = 0.f;
        #pragma unroll
        for (int kf = 0; kf < 8; ++kf)
          #pragma unroll
          for (int e = 0; e < 4; ++e){
            float pv = exp2f(s[kf][qf][e] - m_r[qf]);
            s[kf][qf][e] = pv; ts += pv;
          }
        ts += __shfl_xor(ts, 16); ts += __shfl_xor(ts, 32);
        l_r[qf] += ts;
      }
    }

    // ---- O^T += V^T · P^T via K=16 MFMA; P frags packed in-loop ----
    #pragma unroll
    for (int kf = 0; kf < 8; ++kf){
      u32 PH[2][2], PL[2][2];
      #pragma unroll
      for (int qf = 0; qf < 2; ++qf){
        if (act[qf]){
          float p0 = s[kf][qf][0], p1 = s[kf][qf][1], p2 = s[kf][qf][2], p3 = s[kf][qf][3];
          __bf16 h0=(__bf16)p0, h1=(__bf16)p1, h2=(__bf16)p2, h3=(__bf16)p3;
          PH[qf][0] = pkbf(p0, p1);
          PH[qf][1] = pkbf(p2, p3);
          PL[qf][0] = pkbf(p0-(float)h0, p1-(float)h1);
          PL[qf][1] = pkbf(p2-(float)h2, p3-(float)h3);
        }
      }
      int chunk = 2*kf + (g>>1);
      int pb = (chunk >> 3) << 13;
      int cl = chunk & 7;
      #pragma unroll
      for (int ef = 0; ef < 4; ++ef){
        int rowv = ef*16 + r;
        int off = pb + rowv*128 + ((cl ^ (rowv & 7)) << 4) + (g&1)*8;
        s16x4 vh = *(const s16x4*)(V0 + off);
        s16x4 vl = *(const s16x4*)(V1 + off);
        #pragma unroll
        for (int qf = 0; qf < 2; ++qf){
          if (act[qf]){
            s16x4 ph = mk4(PH[qf][0], PH[qf][1]);
            s16x4 pl = mk4(PL[qf][0], PL[qf][1]);
            ot[ef][qf] = __builtin_amdgcn_mfma_f32_16x16x16bf16_1k(vh, pl, ot[ef][qf], 0,0,0);
            ot[ef][qf] = __builtin_amdgcn_mfma_f32_16x16x16bf16_1k(vl, ph, ot[ef][qf], 0,0,0);
            ot[ef][qf] = __builtin_amdgcn_mfma_f32_16x16x16bf16_1k(vh, ph, ot[ef][qf], 0,0,0);
          }
        }
      }
    }
    __builtin_amdgcn_s_barrier();
  }

  // ---- epilogue: per q-tile O^T -> LDS transpose -> hi/lo bf16 store ----
  float* Osh = (float*)ldsbuf;   // [128][68]
  #pragma unroll
  for (int qf = 0; qf < 2; ++qf){
    float inv = 1.0f / l_r[qf];
    int qloc = (qf ? (7-w) : w)*16 + r;
    #pragma unroll
    for (int ef = 0; ef < 4; ++ef)
      #pragma unroll
      for (int e = 0; e < 4; ++e)
        Osh[qloc*68 + ef*16 + g*4 + e] = ot[ef][qf][e] * inv;
    __syncthreads();
    {
      int qt = qf ? qtB : qtA;
      int q = tid >> 2, e0 = (tid & 3)*16;
      const float* srow = Osh + q*68 + e0;
      size_t base = ((size_t)(b*TSEQ + qt*128 + q))*DD + h*64 + e0;
      #pragma unroll
      for (int j = 0; j < 4; ++j){
        float4 v = *(const float4*)(srow + j*4);
        float f[4] = {v.x, v.y, v.z, v.w};
        __bf16 hb[4] __attribute__((aligned(8)));
        __bf16 lb[4] __attribute__((aligned(8)));
        #pragma unroll
        for (int q2 = 0; q2 < 4; ++q2){
          __bf16 h2b = (__bf16)f[q2];
          hb[q2] = h2b; lb[q2] = (__bf16)(f[q2] - (float)h2b);
        }
        *(uint2*)(ahi + base + j*4) = *(const uint2*)hb;
        *(uint2*)(alo + base + j*4) = *(const uint2*)lb;
      }
    }
    __syncthreads();
  }
}

// ============================================================
// Fused LN2 + Router
// ============================================================
__global__ __launch_bounds__(256) void routerln_kernel(const float* __restrict__ x1,
    const float* __restrict__ gw, const float* __restrict__ bw,
    const float* __restrict__ Wg, const float* __restrict__ bg,
    const float* __restrict__ Wn, const float* __restrict__ bn,
    __bf16* __restrict__ h2b,
    int* __restrict__ idx0, int* __restrict__ idx1,
    float* __restrict__ g0, float* __restrict__ g1)
{
  int wid = threadIdx.x >> 6, lane = threadIdx.x & 63;
  int tok = blockIdx.x*4 + wid;
  const float* xr = x1 + (size_t)tok*DD;
  float4 a = *(const float4*)(xr + lane*4);
  float4 c = *(const float4*)(xr + 256 + lane*4);
  float s  = a.x+a.y+a.z+a.w + c.x+c.y+c.z+c.w;
  float ss = a.x*a.x+a.y*a.y+a.z*a.z+a.w*a.w + c.x*c.x+c.y*c.y+c.z*c.z+c.w*c.w;
  #pragma unroll
  for (int off = 32; off; off >>= 1){ s += __shfl_xor(s, off); ss += __shfl_xor(ss, off); }
  float m   = s * (1.0f/DD);
  float var = ss * (1.0f/DD) - m*m;
  float rr  = 1.0f / sqrtf(var + 1e-5f);
  float4 g1v = *(const float4*)(gw + lane*4);
  float4 b1v = *(const float4*)(bw + lane*4);
  float4 g2v = *(const float4*)(gw + 256 + lane*4);
  float4 b2v = *(const float4*)(bw + 256 + lane*4);
  float f1[4], f2[4];
  f1[0]=(a.x-m)*rr*g1v.x+b1v.x; f1[1]=(a.y-m)*rr*g1v.y+b1v.y; f1[2]=(a.z-m)*rr*g1v.z+b1v.z; f1[3]=(a.w-m)*rr*g1v.w+b1v.w;
  f2[0]=(c.x-m)*rr*g2v.x+b2v.x; f2[1]=(c.y-m)*rr*g2v.y+b2v.y; f2[2]=(c.z-m)*rr*g2v.z+b2v.z; f2[3]=(c.w-m)*rr*g2v.w+b2v.w;
  {
    __bf16 h1v[4] __attribute__((aligned(8)));
    __bf16 h2v[4] __attribute__((aligned(8)));
    #pragma unroll
    for (int j = 0; j < 4; ++j){ h1v[j] = (__bf16)f1[j]; h2v[j] = (__bf16)f2[j]; }
    size_t base = (size_t)tok*DD + lane*4;
    *(uint2*)(h2b + base)       = *(const uint2*)h1v;
    *(uint2*)(h2b + base + 256) = *(const uint2*)h2v;
  }
  float ag[8] = {0,0,0,0,0,0,0,0}, an[8] = {0,0,0,0,0,0,0,0};
  int d1 = lane*4, d2 = 256 + lane*4;
  #pragma unroll
  for (int j = 0; j < 4; ++j){
    const float* wg1 = Wg + (size_t)(d1+j)*8;
    const float* wn1 = Wn + (size_t)(d1+j)*8;
    const float* wg2 = Wg + (size_t)(d2+j)*8;
    const float* wn2 = Wn + (size_t)(d2+j)*8;
    #pragma unroll
    for (int e = 0; e < 8; ++e){
      ag[e] = fmaf(f1[j], wg1[e], ag[e]); an[e] = fmaf(f1[j], wn1[e], an[e]);
      ag[e] = fmaf(f2[j], wg2[e], ag[e]); an[e] = fmaf(f2[j], wn2[e], an[e]);
    }
  }
  #pragma unroll
  for (int off = 32; off; off >>= 1){
    #pragma unroll
    for (int e = 0; e < 8; ++e){ ag[e] += __shfl_xor(ag[e], off); an[e] += __shfl_xor(an[e], off); }
  }
  __shared__ float ns[4][8];
  if (lane < 8){
    int e = lane;
    float lg = ag[e] + bg[e];
    float nl = an[e] + bn[e];
    float sp = fmaxf(nl, 0.f) + log1pf(expf(-fabsf(nl)));
    unsigned i = (unsigned)(tok*8 + e);
    unsigned r0b, r1b;
    threefry2x32(0u, i, r0b, r1b);
    unsigned bits = r0b ^ r1b;
    float f = __uint_as_float((bits >> 9) | 0x3f800000u) - 1.0f;
    float u = fmaf(f, 2.0f, -0.99999994f);
    u = fmaxf(u, -0.99999994f);
    float z = 1.41421356f * erfinv_f(u);
    ns[wid][e] = lg + z*sp;
  }
  __syncthreads();
  if (lane == 0){
    float v0 = -INFINITY; int i0 = 0;
    #pragma unroll
    for (int e = 0; e < 8; ++e){ float v = ns[wid][e]; if (v > v0){ v0 = v; i0 = e; } }
    float v1 = -INFINITY; int i1 = 0;
    #pragma unroll
    for (int e = 0; e < 8; ++e){ if (e != i0){ float v = ns[wid][e]; if (v > v1){ v1 = v; i1 = e; } } }
    float dexp = expf(v1 - v0);
    float ssum = 1.0f + dexp;
    idx0[tok] = i0; idx1[tok] = i1;
    g0[tok] = 1.0f/ssum; g1[tok] = dexp/ssum;
  }
}

// ============================================================
// Capacity routing
// ============================================================
__global__ __launch_bounds__(256) void route_scan(const int* __restrict__ idx0,
    const int* __restrict__ idx1, int* __restrict__ idx_buf, int* __restrict__ tok_slot)
{
  int e = blockIdx.x, tid = threadIdx.x;
  for (int i = tid; i < CAPK; i += 256) idx_buf[e*CAPK + i] = 0;
  __syncthreads();
  int base = tid * 32;
  int cnt = 0;
  for (int j = 0; j < 32; ++j){ int t = base + j; cnt += (idx0[t]==e || idx1[t]==e) ? 1 : 0; }
  __shared__ int ps[256];
  ps[tid] = cnt; __syncthreads();
  for (int off = 1; off < 256; off <<= 1){
    int add = (tid >= off) ? ps[tid - off] : 0;
    __syncthreads();
    ps[tid] += add;
    __syncthreads();
  }
  int slot = ps[tid] - cnt;
  for (int j = 0; j < 32; ++j){
    int t = base + j;
    int k = (idx0[t]==e) ? 0 : ((idx1[t]==e) ? 1 : -1);
    if (k >= 0){
      if (slot < CAPK){ idx_buf[e*CAPK + slot] = t; tok_slot[t*2 + k] = slot; }
      else            { tok_slot[t*2 + k] = -1; }
      slot++;
    }
  }
}

// ============================================================
// Combine (eout bf16)
// ============================================================
__global__ __launch_bounds__(128) void combine_kernel(const float* __restrict__ x1,
    const __bf16* __restrict__ eout, const int* __restrict__ idx0, const int* __restrict__ idx1,
    const float* __restrict__ g0, const float* __restrict__ g1,
    const int* __restrict__ tok_slot, float* __restrict__ outp)
{
  int n = blockIdx.x, t = threadIdx.x;
  float4 acc = *(const float4*)(x1 + (size_t)n*DD + t*4);
  #pragma unroll
  for (int k = 0; k < 2; ++k){
    int s = tok_slot[n*2 + k];
    if (s >= 0){
      int e  = (k==0) ? idx0[n] : idx1[n];
      float g = (k==0) ? g0[n] : g1[n];
      __bf16 vb[4] __attribute__((aligned(8)));
      *(uint2*)vb = *(const uint2*)(eout + ((size_t)(e*CAPK + s))*DD + t*4);
      acc.x = fmaf(g, (float)vb[0], acc.x); acc.y = fmaf(g, (float)vb[1], acc.y);
      acc.z = fmaf(g, (float)vb[2], acc.z); acc.w = fmaf(g, (float)vb[3], acc.w);
    }
  }
  *(float4*)(outp + (size_t)n*DD + t*4) = acc;
}

// ============================================================
extern "C" void kernel_launch(void* const* d_in, const int* in_sizes, int n_in,
                              void* d_out, int out_size, void* d_ws, size_t ws_size,
                              hipStream_t stream)
{
  const float* x    = (const float*)d_in[0];
  const float* ln1g = (const float*)d_in[1];
  const float* ln1b = (const float*)d_in[2];
  const float* Wq   = (const float*)d_in[3];
  const float* Wk   = (const float*)d_in[4];
  const float* Wv   = (const float*)d_in[5];
  const float* Wo   = (const float*)d_in[6];
  const float* bo   = (const float*)d_in[7];
  const float* ln2g = (const float*)d_in[8];
  const float* ln2b = (const float*)d_in[9];
  const float* Wg   = (const float*)d_in[10];
  const float* bg   = (const float*)d_in[11];
  const float* Wn   = (const float*)d_in[12];
  const float* bn   = (const float*)d_in[13];
  const float* W1   = (const float*)d_in[14];
  const float* b1   = (const float*)d_in[15];
  const float* W2   = (const float*)d_in[16];
  const float* b2   = (const float*)d_in[17];
  float* out = (float*)d_out;
  char* ws = (char*)d_ws;
  const size_t MB = 1u << 20;

  // allow 128KB dynamic LDS for attn (ignore result; AMD may not require it)
  (void)hipFuncSetAttribute((const void*)attn_mfma,
      hipFuncAttributeMaxDynamicSharedMemorySize, 131072);

  // workspace layout (time-aliased; peak ~145.5 MiB)
  __bf16* h1hi   = (__bf16*)(ws);             // 0..8   : LN1 hi (s1-3)
  __bf16* h1lo   = (__bf16*)(ws + 8*MB);      // 8..16  : LN1 lo
  __bf16* attnhi = (__bf16*)(ws);             // 0..8   : attn out hi (s4b-5)
  __bf16* attnlo = (__bf16*)(ws + 8*MB);      // 8..16
  __bf16* h2b    = (__bf16*)(ws);             // 0..8   : LN2 out bf16 (s6-10)
  float*  qkv    = (float*)(ws + 16*MB);      // 16..64 : qkv f32 (s3-4b)
  __bf16* W1T    = (__bf16*)(ws + 16*MB);     // 16..32 : (s7-10)
  __bf16* W2T    = (__bf16*)(ws + 32*MB);     // 32..48 : (s7-10)
  __bf16* eoutb  = (__bf16*)(ws + 48*MB);     // 48..64 : expert out bf16 (s10-11)
  float*  x1     = (float*)(ws + 64*MB);      // 64..80 : (s5-11)
  __bf16* Khi    = (__bf16*)(ws + 80*MB);     // 80..88 : (s4a-4b)
  __bf16* Klo    = (__bf16*)(ws + 88*MB);     // 88..96
  __bf16* Vthi   = (__bf16*)(ws + 96*MB);     // 96..104
  __bf16* Vtlo   = (__bf16*)(ws + 104*MB);    // 104..112
  __bf16* Bqh    = (__bf16*)(ws + 80*MB);     // 80..81.5 : qkv W hi (s2-3; dead before s4a)
  __bf16* Bql    = (__bf16*)(ws + 82*MB);     // 82..83.5
  __bf16* mid    = (__bf16*)(ws + 80*MB);     // 80..144 : all-8-expert mid (s10)
  __bf16* WoTh   = (__bf16*)(ws + 144*MB);    // 144..144.5 (s2-5)
  __bf16* WoTl   = (__bf16*)(ws + 144*MB + 512*1024);
  char*   smallp = ws + 145*MB;
  int*   idx0     = (int*)smallp;
  int*   idx1     = idx0 + NTOK;
  float* g0       = (float*)(idx1 + NTOK);
  float* g1       = g0 + NTOK;
  int*   tok_slot = (int*)(g1 + NTOK);
  int*   idx_buf  = tok_slot + NTOK*2;

  // 1. merged prep: LN1 + QKV weight pack + Wo transpose
  prep_kernel<<<dim3(2304), 256, 0, stream>>>(x, ln1g, ln1b, h1hi, h1lo,
      Wq, Wk, Wv, Bqh, Bql, Wo, WoTh, WoTl);
  // 2. QKV projection (bf16x3 MFMA)
  gemm_mfma3<0,0><<<dim3(12,64), 256, 0, stream>>>(h1hi, h1lo, Bqh, Bql, nullptr, nullptr, qkv, NTOK, 1536, DD);
  // 3a. convert K,V -> hi/lo bf16 (V transposed)
  convert_kv<<<dim3(TSEQ/64, 32), 256, 0, stream>>>(qkv, Khi, Klo, Vthi, Vtlo);
  // 3b. causal flash attention (KVBLK=128, dynamic LDS)
  attn_mfma<<<dim3(32, 8), 512, 131072, stream>>>(qkv, Khi, Klo, Vthi, Vtlo, attnhi, attnlo);
  // 4. Wo projection + bias + residual -> x1
  gemm_mfma3<1,1><<<dim3(4,64), 256, 0, stream>>>(attnhi, attnlo, WoTh, WoTl, bo, x, x1, NTOK, DD, DD);
  // 5. fused LN2 + router
  routerln_kernel<<<dim3(NTOK/4), 256, 0, stream>>>(x1, ln2g, ln2b, Wg, bg, Wn, bn,
      h2b, idx0, idx1, g0, g1);
  // 6. expert weights -> bf16 transposed (merged W1+W2)
  transp_conv2<<<dim3(512,1,NE), 256, 0, stream>>>(W1, W2, W1T, W2T);
  // 7. capacity scan
  route_scan<<<dim3(NE), 256, 0, stream>>>(idx0, idx1, idx_buf, tok_slot);
  // 8+9. expert FFN, all 8 experts per launch (e = flat&7 -> one per XCD)
  gemm_mfma<1,1,1,4,3><<<dim3(8*16*16), 256, 0, stream>>>(
      h2b, W1T, b1, mid, idx_buf, CAPK, FF, DD);
  gemm_mfma<1,0,0,2,3><<<dim3(8*16*4), 256, 0, stream>>>(
      mid, W2T, b2, eoutb, nullptr, CAPK, DD, FF);
  // 10. combine + residual
  combine_kernel<<<dim3(NTOK), 128, 0, stream>>>(x1, eoutb, idx0, idx1, g0, g1, tok_slot, out);
}

// Round 11
// 362.924 us; speedup vs baseline: 1.0633x; 1.0115x over previous
//
#include <hip/hip_runtime.h>
#include <math.h>

// ---------------- problem constants ----------------
#define TSEQ 2048
#define DD   512
#define NH   8
#define HSZ  64
#define NE   8
#define NTOK 8192    // B*T
#define CAPK 2048
#define FF   2048    // 4*D

typedef __bf16 bf16x8 __attribute__((ext_vector_type(8)));
typedef float  f32x4  __attribute__((ext_vector_type(4)));
typedef unsigned int u32;
typedef u32 u32x2 __attribute__((ext_vector_type(2)));
typedef short s16x4 __attribute__((ext_vector_type(4)));

#define WAITVM(N) asm volatile("s_waitcnt vmcnt(" #N ")" ::: "memory")

__device__ __forceinline__ void gload16(const void* g, void* l){
  __builtin_amdgcn_global_load_lds((const __attribute__((address_space(1))) u32*)g,
                                   (__attribute__((address_space(3))) u32*)l, 16, 0, 0);
}

__device__ __forceinline__ u32 pkbf(float a, float b){
  unsigned short ua = __builtin_bit_cast(unsigned short, (__bf16)a);
  unsigned short ub = __builtin_bit_cast(unsigned short, (__bf16)b);
  return (u32)ua | ((u32)ub << 16);
}

__device__ __forceinline__ u32 pksplit(float v){
  __bf16 hb = (__bf16)v;
  __bf16 lb = (__bf16)(v - (float)hb);
  return (u32)__builtin_bit_cast(unsigned short, hb) |
         ((u32)__builtin_bit_cast(unsigned short, lb) << 16);
}

__device__ __forceinline__ s16x4 mk4(u32 a, u32 b){
  u32x2 t; t[0] = a; t[1] = b;
  return __builtin_bit_cast(s16x4, t);
}

// ============================================================
// Threefry-2x32, key = (0, 42)
// ============================================================
__device__ __forceinline__ unsigned rotl32(unsigned x, int r){ return (x<<r)|(x>>(32-r)); }

__device__ __forceinline__ void threefry2x32(unsigned c0, unsigned c1, unsigned &o0, unsigned &o1){
  const unsigned k0 = 0u, k1 = 42u;
  const unsigned k2 = k0 ^ k1 ^ 0x1BD11BDAu;
  unsigned x0 = c0 + k0, x1 = c1 + k1;
#define TFR(rot) { x0 += x1; x1 = rotl32(x1, rot); x1 ^= x0; }
  TFR(13) TFR(15) TFR(26) TFR(6)   x0 += k1; x1 += k2 + 1u;
  TFR(17) TFR(29) TFR(16) TFR(24)  x0 += k2; x1 += k0 + 2u;
  TFR(13) TFR(15) TFR(26) TFR(6)   x0 += k0; x1 += k1 + 3u;
  TFR(17) TFR(29) TFR(16) TFR(24)  x0 += k1; x1 += k2 + 4u;
  TFR(13) TFR(15) TFR(26) TFR(6)   x0 += k2; x1 += k0 + 5u;
#undef TFR
  o0 = x0; o1 = x1;
}

__device__ __forceinline__ float erfinv_f(float x){
  float w = -log1pf(-x*x);
  float p;
  if (w < 5.0f){
    w -= 2.5f;
    p = 2.81022636e-08f;
    p = fmaf(p,w, 3.43273939e-07f);
    p = fmaf(p,w,-3.5233877e-06f);
    p = fmaf(p,w,-4.39150654e-06f);
    p = fmaf(p,w, 0.00021858087f);
    p = fmaf(p,w,-0.00125372503f);
    p = fmaf(p,w,-0.00417768164f);
    p = fmaf(p,w, 0.246640727f);
    p = fmaf(p,w, 1.50140941f);
  } else {
    w = sqrtf(w) - 3.0f;
    p = -0.000200214257f;
    p = fmaf(p,w, 0.000100950558f);
    p = fmaf(p,w, 0.00134934322f);
    p = fmaf(p,w,-0.00367342844f);
    p = fmaf(p,w, 0.00573950773f);
    p = fmaf(p,w,-0.0076224613f);
    p = fmaf(p,w, 0.00943887047f);
    p = fmaf(p,w, 1.00167406f);
    p = fmaf(p,w, 2.83297682f);
  }
  return p * x;
}

// ============================================================
// Merged prep: LN1->hi/lo bf16 (blk<2048), pack QKV W (2048..2239),
// transpose+split Wo (2240..2303)
// ============================================================
__global__ __launch_bounds__(256) void prep_kernel(
    const float* __restrict__ x, const float* __restrict__ ln1g, const float* __restrict__ ln1b,
    __bf16* __restrict__ h1hi, __bf16* __restrict__ h1lo,
    const float* __restrict__ Wq, const float* __restrict__ Wk, const float* __restrict__ Wv,
    __bf16* __restrict__ Bqh, __bf16* __restrict__ Bql,
    const float* __restrict__ Wo, __bf16* __restrict__ WoTh, __bf16* __restrict__ WoTl)
{
  __shared__ float t[64][65];
  int blk = blockIdx.x;
  int tid = threadIdx.x;
  if (blk < 2048){
    int row  = blk*4 + (tid >> 6);
    int lane = tid & 63;
    const float* xr = x + (size_t)row*DD;
    float4 a = *(const float4*)(xr + lane*4);
    float4 c = *(const float4*)(xr + 256 + lane*4);
    float s  = a.x+a.y+a.z+a.w + c.x+c.y+c.z+c.w;
    float ss = a.x*a.x+a.y*a.y+a.z*a.z+a.w*a.w + c.x*c.x+c.y*c.y+c.z*c.z+c.w*c.w;
    #pragma unroll
    for (int off = 32; off; off >>= 1){ s += __shfl_xor(s, off); ss += __shfl_xor(ss, off); }
    float m   = s * (1.0f/DD);
    float var = ss * (1.0f/DD) - m*m;
    float r   = 1.0f / sqrtf(var + 1e-5f);
    float4 g1 = *(const float4*)(ln1g + lane*4);
    float4 b1 = *(const float4*)(ln1b + lane*4);
    float4 g2 = *(const float4*)(ln1g + 256 + lane*4);
    float4 b2 = *(const float4*)(ln1b + 256 + lane*4);
    float f1[4], f2[4];
    f1[0]=(a.x-m)*r*g1.x+b1.x; f1[1]=(a.y-m)*r*g1.y+b1.y; f1[2]=(a.z-m)*r*g1.z+b1.z; f1[3]=(a.w-m)*r*g1.w+b1.w;
    f2[0]=(c.x-m)*r*g2.x+b2.x; f2[1]=(c.y-m)*r*g2.y+b2.y; f2[2]=(c.z-m)*r*g2.z+b2.z; f2[3]=(c.w-m)*r*g2.w+b2.w;
    __bf16 h1v[4] __attribute__((aligned(8))), l1v[4] __attribute__((aligned(8)));
    __bf16 h2v[4] __attribute__((aligned(8))), l2v[4] __attribute__((aligned(8)));
    #pragma unroll
    for (int j = 0; j < 4; ++j){
      __bf16 hb = (__bf16)f1[j]; h1v[j]=hb; l1v[j]=(__bf16)(f1[j]-(float)hb);
      __bf16 hc = (__bf16)f2[j]; h2v[j]=hc; l2v[j]=(__bf16)(f2[j]-(float)hc);
    }
    size_t base = (size_t)row*DD + lane*4;
    *(uint2*)(h1hi + base)       = *(const uint2*)h1v;
    *(uint2*)(h1lo + base)       = *(const uint2*)l1v;
    *(uint2*)(h1hi + base + 256) = *(const uint2*)h2v;
    *(uint2*)(h1lo + base + 256) = *(const uint2*)l2v;
  } else if (blk < 2240){
    int bx = blk - 2048;
    int kt = (bx & 7) * 64;
    int z  = bx >> 3;
    int sel = z >> 3, hh = z & 7;
    const float* W = (sel==0 ? Wq : (sel==1 ? Wk : Wv)) + (size_t)hh*DD*HSZ;
    int r = tid>>2, c0 = (tid&3)*16;
    #pragma unroll
    for (int j = 0; j < 16; j += 4){
      float4 v = *(const float4*)&W[(size_t)(kt+r)*HSZ + c0 + j];
      t[r][c0+j]=v.x; t[r][c0+j+1]=v.y; t[r][c0+j+2]=v.z; t[r][c0+j+3]=v.w;
    }
    __syncthreads();
    __bf16 hb[16] __attribute__((aligned(32)));
    __bf16 lb[16] __attribute__((aligned(32)));
    #pragma unroll
    for (int j = 0; j < 16; ++j){
      float f = t[c0+j][r];
      __bf16 h = (__bf16)f; hb[j]=h; lb[j]=(__bf16)(f-(float)h);
    }
    size_t off = (size_t)(z*64 + r)*512 + kt + c0;
    *(uint4*)(Bqh+off) = ((const uint4*)hb)[0]; *(uint4*)(Bqh+off+8) = ((const uint4*)hb)[1];
    *(uint4*)(Bql+off) = ((const uint4*)lb)[0]; *(uint4*)(Bql+off+8) = ((const uint4*)lb)[1];
  } else {
    int bx = blk - 2240;
    int nt = (bx & 7) * 64, mt = (bx >> 3) * 64;
    int r = tid>>2, c0 = (tid&3)*16;
    #pragma unroll
    for (int j = 0; j < 16; j += 4){
      float4 v = *(const float4*)&Wo[(size_t)(mt+r)*DD + nt + c0 + j];
      t[r][c0+j]=v.x; t[r][c0+j+1]=v.y; t[r][c0+j+2]=v.z; t[r][c0+j+3]=v.w;
    }
    __syncthreads();
    __bf16 hb[16] __attribute__((aligned(32)));
    __bf16 lb[16] __attribute__((aligned(32)));
    #pragma unroll
    for (int j = 0; j < 16; ++j){
      float f = t[c0+j][r];
      __bf16 h = (__bf16)f; hb[j]=h; lb[j]=(__bf16)(f-(float)h);
    }
    size_t off = (size_t)(nt + r)*DD + mt + c0;
    *(uint4*)(WoTh+off) = ((const uint4*)hb)[0]; *(uint4*)(WoTh+off+8) = ((const uint4*)hb)[1];
    *(uint4*)(WoTl+off) = ((const uint4*)lb)[0]; *(uint4*)(WoTl+off+8) = ((const uint4*)lb)[1];
  }
}

// ============================================================
// bf16x3 split-precision MFMA GEMM, 2-phase counted-vmcnt,
// 1-D XCD-swizzled grid: all NN n-tiles of an m-panel -> same XCD.
// MODE 0: C f32 = A@B^T + bias + res    (Wo)
// MODE 1: QKV epilogue via LDS: pre-scaled Q hi/lo, K hi/lo, V^T hi/lo
// ============================================================
template<int MODE, int NN>
__global__ __launch_bounds__(256) void gemm_mfma3(
    const __bf16* __restrict__ Ahi, const __bf16* __restrict__ Alo,
    const __bf16* __restrict__ Bhi, const __bf16* __restrict__ Blo,
    const float* __restrict__ bias, const float* __restrict__ res, float* __restrict__ C,
    __bf16* __restrict__ qh, __bf16* __restrict__ ql,
    __bf16* __restrict__ kh, __bf16* __restrict__ kl,
    __bf16* __restrict__ vth, __bf16* __restrict__ vtl,
    int M, int N, int K)
{
  __shared__ __align__(16) char smem[65536];
  __bf16* AsH = (__bf16*)smem;            // [2][4096]
  __bf16* AsL = (__bf16*)(smem + 16384);
  __bf16* BsH = (__bf16*)(smem + 32768);
  __bf16* BsL = (__bf16*)(smem + 49152);

  int flat  = blockIdx.x;
  int chunk = flat / (8*NN);
  int rem   = flat % (8*NN);
  int mloc  = rem & 7;
  int nn    = rem >> 3;
  int m0 = (chunk*8 + mloc)*128;
  int n0 = nn*128;

  int tid = threadIdx.x;
  int w = tid>>6, l = tid&63;
  int wm = w>>1, wn = w&1;
  int srow = w*32 + (l>>2);
  int skb  = (l&3)<<4;
  const char* agh = (const char*)(Ahi + (size_t)(m0+srow)*K) + skb;
  const char* agl = (const char*)(Alo + (size_t)(m0+srow)*K) + skb;
  const char* bgh = (const char*)(Bhi + (size_t)(n0+srow)*K) + skb;
  const char* bgl = (const char*)(Blo + (size_t)(n0+srow)*K) + skb;
  size_t r16 = (size_t)16*K*sizeof(__bf16);

  f32x4 acc[4][4] = {};
  int rl = l & 15, kh_ = l >> 4;
  const __bf16* abh = AsH + (wm*64 + rl)*32 + kh_*8;
  const __bf16* abl = AsL + (wm*64 + rl)*32 + kh_*8;
  const __bf16* bbh = BsH + (wn*64 + rl)*32 + kh_*8;
  const __bf16* bbl = BsL + (wn*64 + rl)*32 + kh_*8;

  auto STAGE = [&](int bb, int kt){
    size_t o = (size_t)kt*64;
    gload16(agh+o,     AsH + bb*4096 + w*1024);
    gload16(agh+o+r16, AsH + bb*4096 + w*1024+512);
    gload16(agl+o,     AsL + bb*4096 + w*1024);
    gload16(agl+o+r16, AsL + bb*4096 + w*1024+512);
    gload16(bgh+o,     BsH + bb*4096 + w*1024);
    gload16(bgh+o+r16, BsH + bb*4096 + w*1024+512);
    gload16(bgl+o,     BsL + bb*4096 + w*1024);
    gload16(bgl+o+r16, BsL + bb*4096 + w*1024+512);
  };

  int nkt = K >> 5;
  STAGE(0, 0);
  for (int kt = 0; kt < nkt; ++kt){
    int bb = kt & 1;
    if (kt + 1 < nkt){ STAGE(bb^1, kt+1); WAITVM(8); }
    else             { WAITVM(0); }
    __builtin_amdgcn_s_barrier();
    bf16x8 afh[4], afl[4], bfh[4], bfl[4];
    #pragma unroll
    for (int i = 0; i < 4; ++i){
      afh[i] = *(const bf16x8*)(abh + bb*4096 + i*512);
      afl[i] = *(const bf16x8*)(abl + bb*4096 + i*512);
      bfh[i] = *(const bf16x8*)(bbh + bb*4096 + i*512);
      bfl[i] = *(const bf16x8*)(bbl + bb*4096 + i*512);
    }
    #pragma unroll
    for (int fm = 0; fm < 4; ++fm)
      #pragma unroll
      for (int fn = 0; fn < 4; ++fn){
        acc[fm][fn] = __builtin_amdgcn_mfma_f32_16x16x32_bf16(afh[fm], bfl[fn], acc[fm][fn], 0, 0, 0);
        acc[fm][fn] = __builtin_amdgcn_mfma_f32_16x16x32_bf16(afl[fm], bfh[fn], acc[fm][fn], 0, 0, 0);
        acc[fm][fn] = __builtin_amdgcn_mfma_f32_16x16x32_bf16(afh[fm], bfh[fn], acc[fm][fn], 0, 0, 0);
      }
    __builtin_amdgcn_s_barrier();
  }

  int ccol = l & 15, cr = (l >> 4) * 4;
  if (MODE == 0){
    #pragma unroll
    for (int fn = 0; fn < 4; ++fn){
      int n = n0 + wn*64 + fn*16 + ccol;
      float bv = bias[n];
      #pragma unroll
      for (int fm = 0; fm < 4; ++fm){
        int mb = m0 + wm*64 + fm*16 + cr;
        #pragma unroll
        for (int r = 0; r < 4; ++r){
          float v = acc[fm][fn][r] + bv + res[(size_t)(mb+r)*N + n];
          C[(size_t)(mb+r)*N + n] = v;
        }
      }
    }
  } else {
    // QKV epilogue: hi|lo packed u32 via LDS, 2 passes, vectorized stores.
    u32 (*eps)[132] = (u32(*)[132])smem;
    int sel = n0 >> 9;                 // 0=Q,1=K,2=V
    int b   = m0 >> 11;
    int tb  = m0 & 2047;
    int dbase = n0 & 511;
    const float qsc = 0.04419417382415922f * 1.4426950408889634f;  // D^-0.5 * log2(e)
    float sc = (sel == 0) ? qsc : 1.0f;
    #pragma unroll
    for (int p = 0; p < 2; ++p){
      __syncthreads();
      if (sel < 2){
        if (wm == p){
          #pragma unroll
          for (int fm = 0; fm < 4; ++fm)
            #pragma unroll
            for (int fn = 0; fn < 4; ++fn)
              #pragma unroll
              for (int r = 0; r < 4; ++r)
                eps[fm*16 + cr + r][wn*64 + fn*16 + ccol] = pksplit(acc[fm][fn][r] * sc);
        }
        __syncthreads();
        int row = tid >> 2, q4 = tid & 3;
        int hh = (dbase >> 6) + (q4 >> 1);
        int e0 = (q4 & 1) * 32;
        const u32* src = &eps[row][q4*32];
        __bf16 hbuf[32] __attribute__((aligned(16)));
        __bf16 lbuf[32] __attribute__((aligned(16)));
        #pragma unroll
        for (int j = 0; j < 32; ++j){
          u32 pk = src[j];
          hbuf[j] = __builtin_bit_cast(__bf16, (unsigned short)(pk & 0xffffu));
          lbuf[j] = __builtin_bit_cast(__bf16, (unsigned short)(pk >> 16));
        }
        size_t off = ((size_t)(b*8 + hh)*TSEQ + tb + p*64 + row)*64 + e0;
        __bf16* dh = sel ? kh : qh;
        __bf16* dl = sel ? kl : ql;
        #pragma unroll
        for (int j = 0; j < 4; ++j){
          *(uint4*)(dh + off + j*8) = ((const uint4*)hbuf)[j];
          *(uint4*)(dl + off + j*8) = ((const uint4*)lbuf)[j];
        }
      } else {
        if (wn == p){
          #pragma unroll
          for (int fn = 0; fn < 4; ++fn)
            #pragma unroll
            for (int fm = 0; fm < 4; ++fm){
              u32 pk4[4] __attribute__((aligned(16)));
              #pragma unroll
              for (int r = 0; r < 4; ++r)
                pk4[r] = pksplit(acc[fm][fn][r]);
              *(uint4*)&eps[fn*16 + ccol][wm*64 + fm*16 + cr] = *(const uint4*)pk4;
            }
        }
        __syncthreads();
        int col = tid >> 2, tq = tid & 3;
        int d = dbase + p*64 + col;
        int hh = d >> 6, e = d & 63;
        const u32* src = &eps[col][tq*32];
        __bf16 hbuf[32] __attribute__((aligned(16)));
        __bf16 lbuf[32] __attribute__((aligned(16)));
        #pragma unroll
        for (int j = 0; j < 32; ++j){
          u32 pk = src[j];
          hbuf[j] = __builtin_bit_cast(__bf16, (unsigned short)(pk & 0xffffu));
          lbuf[j] = __builtin_bit_cast(__bf16, (unsigned short)(pk >> 16));
        }
        size_t off = ((size_t)(b*8 + hh)*64 + e)*TSEQ + tb + tq*32;
        #pragma unroll
        for (int j = 0; j < 4; ++j){
          *(uint4*)(vth + off + j*8) = ((const uint4*)hbuf)[j];
          *(uint4*)(vtl + off + j*8) = ((const uint4*)lbuf)[j];
        }
      }
    }
  }
}

// ============================================================
// bf16 MFMA GEMM (experts), 2-phase counted-vmcnt, XCD-local experts.
// ============================================================
template<int STORE_BF16, int RELU, int GATHER, int LOGN, int EBITS>
__global__ __launch_bounds__(256) void gemm_mfma(
    const __bf16* __restrict__ A, const __bf16* __restrict__ Bt,
    const float* __restrict__ bias, void* __restrict__ Cv,
    const int* __restrict__ idxb, int M, int N, int K)
{
  __shared__ __bf16 Asl[2][4096];
  __shared__ __bf16 Bsl[2][4096];
  int flat = blockIdx.x;
  int e = flat & ((1<<EBITS)-1);
  int tile = flat >> EBITS;
  int n0 = (tile & ((1<<LOGN)-1)) * 128;
  int m0 = (tile >> LOGN) * 128;
  const __bf16* Be = Bt + (size_t)e*N*K;
  const float*  be = bias + (size_t)e*N;
  int tid = threadIdx.x;
  int w = tid>>6, l = tid&63;
  int wm = w>>1, wn = w&1;
  int srow = w*32 + (l>>2);
  int skb  = (l&3)<<4;
  const char* ag;
  if (GATHER){
    int tok = idxb[e*CAPK + m0 + srow];
    ag = (const char*)(A + (size_t)tok*K) + skb;
  } else {
    ag = (const char*)(A + (size_t)e*M*K + (size_t)(m0 + srow)*K) + skb;
  }
  const char* bg = (const char*)(Be + (size_t)(n0 + srow)*K) + skb;
  size_t r16;
  if (GATHER){
    int tok2 = idxb[e*CAPK + m0 + srow + 16];
    r16 = (size_t)((const char*)(A + (size_t)tok2*K) + skb - ag);
  } else {
    r16 = (size_t)16*K*sizeof(__bf16);
  }

  f32x4 acc[4][4] = {};
  int rl = l & 15, kh = l >> 4;
  const __bf16* abase = &Asl[0][(wm*64 + rl)*32 + kh*8];
  const __bf16* bbase = &Bsl[0][(wn*64 + rl)*32 + kh*8];

  size_t br16 = (size_t)16*K*sizeof(__bf16);
  auto STAGE = [&](int bb, int kt){
    size_t o = (size_t)kt*64;
    gload16(ag+o,      &Asl[bb][w*1024]);
    gload16(ag+o+r16,  &Asl[bb][w*1024+512]);
    gload16(bg+o,      &Bsl[bb][w*1024]);
    gload16(bg+o+br16, &Bsl[bb][w*1024+512]);
  };

  int nkt = K >> 5;
  STAGE(0, 0);
  for (int kt = 0; kt < nkt; ++kt){
    int bb = kt & 1;
    if (kt + 1 < nkt){ STAGE(bb^1, kt+1); WAITVM(4); }
    else             { WAITVM(0); }
    __builtin_amdgcn_s_barrier();
    bf16x8 af[4], bf[4];
    #pragma unroll
    for (int i = 0; i < 4; ++i){
      af[i] = *(const bf16x8*)(abase + bb*4096 + i*512);
      bf[i] = *(const bf16x8*)(bbase + bb*4096 + i*512);
    }
    #pragma unroll
    for (int fm = 0; fm < 4; ++fm)
      #pragma unroll
      for (int fn = 0; fn < 4; ++fn)
        acc[fm][fn] = __builtin_amdgcn_mfma_f32_16x16x32_bf16(af[fm], bf[fn], acc[fm][fn], 0, 0, 0);
    __builtin_amdgcn_s_barrier();
  }

  int ccol = l & 15, cr = (l >> 4) * 4;
  char* Ce = (char*)Cv + (size_t)e*M*N*(STORE_BF16 ? 2 : 4);
  #pragma unroll
  for (int fn = 0; fn < 4; ++fn){
    int n = n0 + wn*64 + fn*16 + ccol;
    float bv = be[n];
    #pragma unroll
    for (int fm = 0; fm < 4; ++fm){
      int mb = m0 + wm*64 + fm*16 + cr;
      #pragma unroll
      for (int r = 0; r < 4; ++r){
        float v = acc[fm][fn][r] + bv;
        if (RELU) v = fmaxf(v, 0.f);
        if (STORE_BF16) ((__bf16*)Ce)[(size_t)(mb+r)*N + n] = (__bf16)v;
        else            ((float*)Ce)[(size_t)(mb+r)*N + n] = v;
      }
    }
  }
}

// ============================================================
// Merged transpose+convert W1,W2 (f32 -> plain bf16 [N][K])
// ============================================================
__global__ __launch_bounds__(256) void transp_conv2(const float* __restrict__ W1,
    const float* __restrict__ W2, __bf16* __restrict__ d1, __bf16* __restrict__ d2)
{
  __shared__ __bf16 t[64][72];
  int e = blockIdx.z;
  int id = blockIdx.x;
  const float* s; __bf16* d; int Ms, Ns, mt, nt;
  if (id < 256){ s = W1; d = d1; Ms = DD; Ns = FF; nt = (id&31)*64; mt = (id>>5)*64; }
  else { int i2 = id-256; s = W2; d = d2; Ms = FF; Ns = DD; nt = (i2&7)*64; mt = (i2>>3)*64; }
  s += (size_t)e*Ms*Ns;
  d += (size_t)e*Ms*Ns;
  int tid = threadIdx.x;
  int r = tid>>2, c0 = (tid&3)*16;
  #pragma unroll
  for (int j = 0; j < 16; j += 4){
    float4 v = *(const float4*)&s[(size_t)(mt+r)*Ns + nt + c0 + j];
    t[r][c0+j]   = (__bf16)v.x; t[r][c0+j+1] = (__bf16)v.y;
    t[r][c0+j+2] = (__bf16)v.z; t[r][c0+j+3] = (__bf16)v.w;
  }
  __syncthreads();
  __bf16 tmp[16] __attribute__((aligned(32)));
  #pragma unroll
  for (int j = 0; j < 16; ++j) tmp[j] = t[c0+j][r];
  uint4* dp = (uint4*)&d[(size_t)(nt+r)*Ms + mt + c0];
  dp[0] = ((const uint4*)tmp)[0];
  dp[1] = ((const uint4*)tmp)[1];
}

// ============================================================
// bf16x3 MFMA flash attention, KVBLK=128, dynamic LDS 128KB.
// Q/K/V all pre-split bf16 hi/lo (Q pre-scaled, exp2 domain).
// ============================================================
__global__ __launch_bounds__(512) void attn_mfma(
    const __bf16* __restrict__ qhi_g, const __bf16* __restrict__ qlo_g,
    const __bf16* __restrict__ khi_g, const __bf16* __restrict__ klo_g,
    const __bf16* __restrict__ vthi_g, const __bf16* __restrict__ vtlo_g,
    __bf16* __restrict__ ahi, __bf16* __restrict__ alo)
{
  extern __shared__ __align__(16) char ldsbuf[];
  int bh = blockIdx.x;
  int qtA = blockIdx.y, qtB = 15 - qtA;      // 128-row q-tiles
  int b = bh >> 3, h = bh & 7;
  int tid = threadIdx.x;
  int w = tid >> 6, l = tid & 63;
  int g = l >> 4, r = l & 15;

  int qb[2]; qb[0] = qtA*128 + w*16; qb[1] = qtB*128 + (7-w)*16;
  int kdiag[2]; kdiag[0] = qtA; kdiag[1] = qtB;

  bf16x8 qhi[2][2], qlo[2][2];
  #pragma unroll
  for (int qf = 0; qf < 2; ++qf)
    #pragma unroll
    for (int ks = 0; ks < 2; ++ks){
      size_t qoff = ((size_t)bh*TSEQ + qb[qf] + r)*64 + ks*32 + g*8;
      qhi[qf][ks] = *(const bf16x8*)(qhi_g + qoff);
      qlo[qf][ks] = *(const bf16x8*)(qlo_g + qoff);
    }

  f32x4 ot[4][2] = {};
  float m_r[2] = {-INFINITY, -INFINITY};
  float l_r[2] = {0.f, 0.f};

  int nkt = qtB + 1;
  size_t kbase = (size_t)bh*TSEQ*64;
  size_t vbase = (size_t)bh*64*TSEQ;

  auto STAGE = [&](int buf, int kt){
    int row = tid >> 3, cc = tid & 7;
    char* base = ldsbuf + buf*65536 + (w << 10);
    #pragma unroll
    for (int p = 0; p < 2; ++p){
      int krow = p*64 + row;
      int ksw = (cc ^ (krow & 7)) * 8;
      gload16(khi_g + kbase + (size_t)(kt*128 + krow)*64 + ksw, base + p*8192);
      gload16(klo_g + kbase + (size_t)(kt*128 + krow)*64 + ksw, base + 16384 + p*8192);
      int vch = p*8 + cc;
      int vsw = ((vch ^ (row & 7)) & 15) * 8;
      gload16(vthi_g + vbase + (size_t)row*TSEQ + kt*128 + vsw, base + 32768 + p*8192);
      gload16(vtlo_g + vbase + (size_t)row*TSEQ + kt*128 + vsw, base + 49152 + p*8192);
    }
  };

  STAGE(0, 0);

  for (int kt = 0; kt < nkt; ++kt){
    int buf = kt & 1;
    if (kt + 1 < nkt){ STAGE(buf ^ 1, kt + 1); WAITVM(8); }
    else             { WAITVM(0); }
    __builtin_amdgcn_s_barrier();

    bool act[2];
    act[0] = (kt <= kdiag[0]);
    act[1] = true;

    const char* K0 = ldsbuf + buf*65536;
    const char* K1 = K0 + 16384;
    const char* V0 = K0 + 32768;
    const char* V1 = K0 + 49152;

    // ---- S^T = K · Q^T (bf16x3), 8 key-frags ----
    f32x4 s[8][2] = {};
    #pragma unroll
    for (int kf = 0; kf < 8; ++kf){
      int rowk = kf*16 + r;
      int rsw = (rowk & 7) << 4;
      #pragma unroll
      for (int ks = 0; ks < 2; ++ks){
        int off = rowk*128 + ((((ks*4 + g) << 4)) ^ rsw);
        bf16x8 khf = *(const bf16x8*)(K0 + off);
        bf16x8 klf = *(const bf16x8*)(K1 + off);
        #pragma unroll
        for (int qf = 0; qf < 2; ++qf){
          if (act[qf]){
            s[kf][qf] = __builtin_amdgcn_mfma_f32_16x16x32_bf16(khf, qlo[qf][ks], s[kf][qf], 0,0,0);
            s[kf][qf] = __builtin_amdgcn_mfma_f32_16x16x32_bf16(klf, qhi[qf][ks], s[kf][qf], 0,0,0);
            s[kf][qf] = __builtin_amdgcn_mfma_f32_16x16x32_bf16(khf, qhi[qf][ks], s[kf][qf], 0,0,0);
          }
        }
      }
    }

    // ---- mask (diag tile) + online softmax over 128 keys (exp2, defer-max) ----
    #pragma unroll
    for (int qf = 0; qf < 2; ++qf){
      if (act[qf]){
        int q = qb[qf] + r;
        float mx = -INFINITY;
        if (kt == kdiag[qf]){
          #pragma unroll
          for (int kf = 0; kf < 8; ++kf)
            #pragma unroll
            for (int e = 0; e < 4; ++e){
              int key = kt*128 + kf*16 + g*4 + e;
              float sv = (key <= q) ? s[kf][qf][e] : -INFINITY;
              s[kf][qf][e] = sv;
              mx = fmaxf(mx, sv);
            }
        } else {
          #pragma unroll
          for (int kf = 0; kf < 8; ++kf)
            #pragma unroll
            for (int e = 0; e < 4; ++e)
              mx = fmaxf(mx, s[kf][qf][e]);
        }
        mx = fmaxf(mx, __shfl_xor(mx, 16));
        mx = fmaxf(mx, __shfl_xor(mx, 32));
        if (__any(mx > m_r[qf])){
          float mn = fmaxf(m_r[qf], mx);
          float fj = exp2f(m_r[qf] - mn);
          m_r[qf] = mn;
          l_r[qf] *= fj;
          #pragma unroll
          for (int ef = 0; ef < 4; ++ef)
            #pragma unroll
            for (int e = 0; e < 4; ++e)
              ot[ef][qf][e] *= fj;
        }
        float ts = 0.f;
        #pragma unroll
        for (int kf = 0; kf < 8; ++kf)
          #pragma unroll
          for (int e = 0; e < 4; ++e){
            float pv = exp2f(s[kf][qf][e] - m_r[qf]);
            s[kf][qf][e] = pv; ts += pv;
          }
        ts += __shfl_xor(ts, 16); ts += __shfl_xor(ts, 32);
        l_r[qf] += ts;
      }
    }

    // ---- O^T += V^T · P^T via K=16 MFMA; P frags packed in-loop ----
    #pragma unroll
    for (int kf = 0; kf < 8; ++kf){
      u32 PH[2][2], PL[2][2];
      #pragma unroll
      for (int qf = 0; qf < 2; ++qf){
        if (act[qf]){
          float p0 = s[kf][qf][0], p1 = s[kf][qf][1], p2 = s[kf][qf][2], p3 = s[kf][qf][3];
          __bf16 h0=(__bf16)p0, h1=(__bf16)p1, h2=(__bf16)p2, h3=(__bf16)p3;
          PH[qf][0] = pkbf(p0, p1);
          PH[qf][1] = pkbf(p2, p3);
          PL[qf][0] = pkbf(p0-(float)h0, p1-(float)h1);
          PL[qf][1] = pkbf(p2-(float)h2, p3-(float)h3);
        }
      }
      int chunk = 2*kf + (g>>1);
      int pb = (chunk >> 3) << 13;
      int cl = chunk & 7;
      #pragma unroll
      for (int ef = 0; ef < 4; ++ef){
        int rowv = ef*16 + r;
        int off = pb + rowv*128 + ((cl ^ (rowv & 7)) << 4) + (g&1)*8;
        s16x4 vh = *(const s16x4*)(V0 + off);
        s16x4 vl = *(const s16x4*)(V1 + off);
        #pragma unroll
        for (int qf = 0; qf < 2; ++qf){
          if (act[qf]){
            s16x4 ph = mk4(PH[qf][0], PH[qf][1]);
            s16x4 pl = mk4(PL[qf][0], PL[qf][1]);
            ot[ef][qf] = __builtin_amdgcn_mfma_f32_16x16x16bf16_1k(vh, pl, ot[ef][qf], 0,0,0);
            ot[ef][qf] = __builtin_amdgcn_mfma_f32_16x16x16bf16_1k(vl, ph, ot[ef][qf], 0,0,0);
            ot[ef][qf] = __builtin_amdgcn_mfma_f32_16x16x16bf16_1k(vh, ph, ot[ef][qf], 0,0,0);
          }
        }
      }
    }
    __builtin_amdgcn_s_barrier();
  }

  // ---- epilogue ----
  float* Osh = (float*)ldsbuf;   // [128][68]
  #pragma unroll
  for (int qf = 0; qf < 2; ++qf){
    float inv = 1.0f / l_r[qf];
    int qloc = (qf ? (7-w) : w)*16 + r;
    #pragma unroll
    for (int ef = 0; ef < 4; ++ef)
      #pragma unroll
      for (int e = 0; e < 4; ++e)
        Osh[qloc*68 + ef*16 + g*4 + e] = ot[ef][qf][e] * inv;
    __syncthreads();
    {
      int qt = qf ? qtB : qtA;
      int q = tid >> 2, e0 = (tid & 3)*16;
      const float* srow = Osh + q*68 + e0;
      size_t base = ((size_t)(b*TSEQ + qt*128 + q))*DD + h*64 + e0;
      #pragma unroll
      for (int j = 0; j < 4; ++j){
        float4 v = *(const float4*)(srow + j*4);
        float f[4] = {v.x, v.y, v.z, v.w};
        __bf16 hb[4] __attribute__((aligned(8)));
        __bf16 lb[4] __attribute__((aligned(8)));
        #pragma unroll
        for (int q2 = 0; q2 < 4; ++q2){
          __bf16 h2b = (__bf16)f[q2];
          hb[q2] = h2b; lb[q2] = (__bf16)(f[q2] - (float)h2b);
        }
        *(uint2*)(ahi + base + j*4) = *(const uint2*)hb;
        *(uint2*)(alo + base + j*4) = *(const uint2*)lb;
      }
    }
    __syncthreads();
  }
}

// ============================================================
// Fused LN2 + Router
// ============================================================
__global__ __launch_bounds__(256) void routerln_kernel(const float* __restrict__ x1,
    const float* __restrict__ gw, const float* __restrict__ bw,
    const float* __restrict__ Wg, const float* __restrict__ bg,
    const float* __restrict__ Wn, const float* __restrict__ bn,
    __bf16* __restrict__ h2b,
    int* __restrict__ idx0, int* __restrict__ idx1,
    float* __restrict__ g0, float* __restrict__ g1)
{
  int wid = threadIdx.x >> 6, lane = threadIdx.x & 63;
  int tok = blockIdx.x*4 + wid;
  const float* xr = x1 + (size_t)tok*DD;
  float4 a = *(const float4*)(xr + lane*4);
  float4 c = *(const float4*)(xr + 256 + lane*4);
  float s  = a.x+a.y+a.z+a.w + c.x+c.y+c.z+c.w;
  float ss = a.x*a.x+a.y*a.y+a.z*a.z+a.w*a.w + c.x*c.x+c.y*c.y+c.z*c.z+c.w*c.w;
  #pragma unroll
  for (int off = 32; off; off >>= 1){ s += __shfl_xor(s, off); ss += __shfl_xor(ss, off); }
  float m   = s * (1.0f/DD);
  float var = ss * (1.0f/DD) - m*m;
  float rr  = 1.0f / sqrtf(var + 1e-5f);
  float4 g1v = *(const float4*)(gw + lane*4);
  float4 b1v = *(const float4*)(bw + lane*4);
  float4 g2v = *(const float4*)(gw + 256 + lane*4);
  float4 b2v = *(const float4*)(bw + 256 + lane*4);
  float f1[4], f2[4];
  f1[0]=(a.x-m)*rr*g1v.x+b1v.x; f1[1]=(a.y-m)*rr*g1v.y+b1v.y; f1[2]=(a.z-m)*rr*g1v.z+b1v.z; f1[3]=(a.w-m)*rr*g1v.w+b1v.w;
  f2[0]=(c.x-m)*rr*g2v.x+b2v.x; f2[1]=(c.y-m)*rr*g2v.y+b2v.y; f2[2]=(c.z-m)*rr*g2v.z+b2v.z; f2[3]=(c.w-m)*rr*g2v.w+b2v.w;
  {
    __bf16 h1v[4] __attribute__((aligned(8)));
    __bf16 h2v[4] __attribute__((aligned(8)));
    #pragma unroll
    for (int j = 0; j < 4; ++j){ h1v[j] = (__bf16)f1[j]; h2v[j] = (__bf16)f2[j]; }
    size_t base = (size_t)tok*DD + lane*4;
    *(uint2*)(h2b + base)       = *(const uint2*)h1v;
    *(uint2*)(h2b + base + 256) = *(const uint2*)h2v;
  }
  float ag[8] = {0,0,0,0,0,0,0,0}, an[8] = {0,0,0,0,0,0,0,0};
  int d1 = lane*4, d2 = 256 + lane*4;
  #pragma unroll
  for (int j = 0; j < 4; ++j){
    const float* wg1 = Wg + (size_t)(d1+j)*8;
    const float* wn1 = Wn + (size_t)(d1+j)*8;
    const float* wg2 = Wg + (size_t)(d2+j)*8;
    const float* wn2 = Wn + (size_t)(d2+j)*8;
    #pragma unroll
    for (int e = 0; e < 8; ++e){
      ag[e] = fmaf(f1[j], wg1[e], ag[e]); an[e] = fmaf(f1[j], wn1[e], an[e]);
      ag[e] = fmaf(f2[j], wg2[e], ag[e]); an[e] = fmaf(f2[j], wn2[e], an[e]);
    }
  }
  #pragma unroll
  for (int off = 32; off; off >>= 1){
    #pragma unroll
    for (int e = 0; e < 8; ++e){ ag[e] += __shfl_xor(ag[e], off); an[e] += __shfl_xor(an[e], off); }
  }
  __shared__ float ns[4][8];
  if (lane < 8){
    int e = lane;
    float lg = ag[e] + bg[e];
    float nl = an[e] + bn[e];
    float sp = fmaxf(nl, 0.f) + log1pf(expf(-fabsf(nl)));
    unsigned i = (unsigned)(tok*8 + e);
    unsigned r0b, r1b;
    threefry2x32(0u, i, r0b, r1b);
    unsigned bits = r0b ^ r1b;
    float f = __uint_as_float((bits >> 9) | 0x3f800000u) - 1.0f;
    float u = fmaf(f, 2.0f, -0.99999994f);
    u = fmaxf(u, -0.99999994f);
    float z = 1.41421356f * erfinv_f(u);
    ns[wid][e] = lg + z*sp;
  }
  __syncthreads();
  if (lane == 0){
    float v0 = -INFINITY; int i0 = 0;
    #pragma unroll
    for (int e = 0; e < 8; ++e){ float v = ns[wid][e]; if (v > v0){ v0 = v; i0 = e; } }
    float v1 = -INFINITY; int i1 = 0;
    #pragma unroll
    for (int e = 0; e < 8; ++e){ if (e != i0){ float v = ns[wid][e]; if (v > v1){ v1 = v; i1 = e; } } }
    float dexp = expf(v1 - v0);
    float ssum = 1.0f + dexp;
    idx0[tok] = i0; idx1[tok] = i1;
    g0[tok] = 1.0f/ssum; g1[tok] = dexp/ssum;
  }
}

// ============================================================
// Capacity routing
// ============================================================
__global__ __launch_bounds__(256) void route_scan(const int* __restrict__ idx0,
    const int* __restrict__ idx1, int* __restrict__ idx_buf, int* __restrict__ tok_slot)
{
  int e = blockIdx.x, tid = threadIdx.x;
  for (int i = tid; i < CAPK; i += 256) idx_buf[e*CAPK + i] = 0;
  __syncthreads();
  int base = tid * 32;
  int cnt = 0;
  for (int j = 0; j < 32; ++j){ int t = base + j; cnt += (idx0[t]==e || idx1[t]==e) ? 1 : 0; }
  __shared__ int ps[256];
  ps[tid] = cnt; __syncthreads();
  for (int off = 1; off < 256; off <<= 1){
    int add = (tid >= off) ? ps[tid - off] : 0;
    __syncthreads();
    ps[tid] += add;
    __syncthreads();
  }
  int slot = ps[tid] - cnt;
  for (int j = 0; j < 32; ++j){
    int t = base + j;
    int k = (idx0[t]==e) ? 0 : ((idx1[t]==e) ? 1 : -1);
    if (k >= 0){
      if (slot < CAPK){ idx_buf[e*CAPK + slot] = t; tok_slot[t*2 + k] = slot; }
      else            { tok_slot[t*2 + k] = -1; }
      slot++;
    }
  }
}

// ============================================================
// Combine (eout bf16)
// ============================================================
__global__ __launch_bounds__(128) void combine_kernel(const float* __restrict__ x1,
    const __bf16* __restrict__ eout, const int* __restrict__ idx0, const int* __restrict__ idx1,
    const float* __restrict__ g0, const float* __restrict__ g1,
    const int* __restrict__ tok_slot, float* __restrict__ outp)
{
  int n = blockIdx.x, t = threadIdx.x;
  float4 acc = *(const float4*)(x1 + (size_t)n*DD + t*4);
  #pragma unroll
  for (int k = 0; k < 2; ++k){
    int s = tok_slot[n*2 + k];
    if (s >= 0){
      int e  = (k==0) ? idx0[n] : idx1[n];
      float g = (k==0) ? g0[n] : g1[n];
      __bf16 vb[4] __attribute__((aligned(8)));
      *(uint2*)vb = *(const uint2*)(eout + ((size_t)(e*CAPK + s))*DD + t*4);
      acc.x = fmaf(g, (float)vb[0], acc.x); acc.y = fmaf(g, (float)vb[1], acc.y);
      acc.z = fmaf(g, (float)vb[2], acc.z); acc.w = fmaf(g, (float)vb[3], acc.w);
    }
  }
  *(float4*)(outp + (size_t)n*DD + t*4) = acc;
}

// ============================================================
extern "C" void kernel_launch(void* const* d_in, const int* in_sizes, int n_in,
                              void* d_out, int out_size, void* d_ws, size_t ws_size,
                              hipStream_t stream)
{
  const float* x    = (const float*)d_in[0];
  const float* ln1g = (const float*)d_in[1];
  const float* ln1b = (const float*)d_in[2];
  const float* Wq   = (const float*)d_in[3];
  const float* Wk   = (const float*)d_in[4];
  const float* Wv   = (const float*)d_in[5];
  const float* Wo   = (const float*)d_in[6];
  const float* bo   = (const float*)d_in[7];
  const float* ln2g = (const float*)d_in[8];
  const float* ln2b = (const float*)d_in[9];
  const float* Wg   = (const float*)d_in[10];
  const float* bg   = (const float*)d_in[11];
  const float* Wn   = (const float*)d_in[12];
  const float* bn   = (const float*)d_in[13];
  const float* W1   = (const float*)d_in[14];
  const float* b1   = (const float*)d_in[15];
  const float* W2   = (const float*)d_in[16];
  const float* b2   = (const float*)d_in[17];
  float* out = (float*)d_out;
  char* ws = (char*)d_ws;
  const size_t MB = 1u << 20;

  (void)hipFuncSetAttribute((const void*)attn_mfma,
      hipFuncAttributeMaxDynamicSharedMemorySize, 131072);

  // workspace layout (time-aliased; peak ~145.5 MiB)
  __bf16* h1hi   = (__bf16*)(ws);             // 0..8   : LN1 hi (s1-2)
  __bf16* h1lo   = (__bf16*)(ws + 8*MB);      // 8..16  : LN1 lo
  __bf16* attnhi = (__bf16*)(ws);             // 0..8   : attn out hi (s3-4)
  __bf16* attnlo = (__bf16*)(ws + 8*MB);      // 8..16
  __bf16* h2b    = (__bf16*)(ws);             // 0..8   : LN2 out bf16 (s5-8)
  __bf16* Qhi    = (__bf16*)(ws + 16*MB);     // 16..24 (s2-3)
  __bf16* Qlo    = (__bf16*)(ws + 24*MB);     // 24..32
  __bf16* Khi    = (__bf16*)(ws + 32*MB);     // 32..40
  __bf16* Klo    = (__bf16*)(ws + 40*MB);     // 40..48
  __bf16* Vthi   = (__bf16*)(ws + 48*MB);     // 48..56
  __bf16* Vtlo   = (__bf16*)(ws + 56*MB);     // 56..64
  __bf16* W1T    = (__bf16*)(ws + 16*MB);     // 16..32 (s6-8; over Q, dead after attn)
  __bf16* W2T    = (__bf16*)(ws + 32*MB);     // 32..48 (over K, dead)
  __bf16* eoutb  = (__bf16*)(ws + 48*MB);     // 48..64 (s9-10; over V, dead)
  float*  x1     = (float*)(ws + 64*MB);      // 64..80 (s4-10)
  __bf16* Bqh    = (__bf16*)(ws + 80*MB);     // 80..81.5 (s1-2)
  __bf16* Bql    = (__bf16*)(ws + 82*MB);     // 82..83.5
  __bf16* mid    = (__bf16*)(ws + 80*MB);     // 80..144 (s8-9; Bq dead)
  __bf16* WoTh   = (__bf16*)(ws + 144*MB);    // 144..144.5 (s1-4)
  __bf16* WoTl   = (__bf16*)(ws + 144*MB + 512*1024);
  char*   smallp = ws + 145*MB;
  int*   idx0     = (int*)smallp;
  int*   idx1     = idx0 + NTOK;
  float* g0       = (float*)(idx1 + NTOK);
  float* g1       = g0 + NTOK;
  int*   tok_slot = (int*)(g1 + NTOK);
  int*   idx_buf  = tok_slot + NTOK*2;

  // 1. merged prep: LN1 + QKV weight pack + Wo transpose
  prep_kernel<<<dim3(2304), 256, 0, stream>>>(x, ln1g, ln1b, h1hi, h1lo,
      Wq, Wk, Wv, Bqh, Bql, Wo, WoTh, WoTl);
  // 2. QKV projection (bf16x3 MFMA) with fused split/transpose LDS epilogue
  gemm_mfma3<1,12><<<dim3(64*12), 256, 0, stream>>>(h1hi, h1lo, Bqh, Bql,
      nullptr, nullptr, nullptr, Qhi, Qlo, Khi, Klo, Vthi, Vtlo, NTOK, 1536, DD);
  // 3. causal flash attention (KVBLK=128, all-bf16 inputs)
  attn_mfma<<<dim3(32, 8), 512, 131072, stream>>>(Qhi, Qlo, Khi, Klo, Vthi, Vtlo, attnhi, attnlo);
  // 4. Wo projection + bias + residual -> x1
  gemm_mfma3<0,4><<<dim3(64*4), 256, 0, stream>>>(attnhi, attnlo, WoTh, WoTl,
      bo, x, x1, nullptr, nullptr, nullptr, nullptr, nullptr, nullptr, NTOK, DD, DD);
  // 5. fused LN2 + router
  routerln_kernel<<<dim3(NTOK/4), 256, 0, stream>>>(x1, ln2g, ln2b, Wg, bg, Wn, bn,
      h2b, idx0, idx1, g0, g1);
  // 6. expert weights -> bf16 transposed (merged W1+W2)
  transp_conv2<<<dim3(512,1,NE), 256, 0, stream>>>(W1, W2, W1T, W2T);
  // 7. capacity scan
  route_scan<<<dim3(NE), 256, 0, stream>>>(idx0, idx1, idx_buf, tok_slot);
  // 8+9. expert FFN, all 8 experts per launch (e = flat&7 -> one per XCD)
  gemm_mfma<1,1,1,4,3><<<dim3(8*16*16), 256, 0, stream>>>(
      h2b, W1T, b1, mid, idx_buf, CAPK, FF, DD);
  gemm_mfma<1,0,0,2,3><<<dim3(8*16*4), 256, 0, stream>>>(
      mid, W2T, b2, eoutb, nullptr, CAPK, DD, FF);
  // 10. combine + residual
  combine_kernel<<<dim3(NTOK), 128, 0, stream>>>(x1, eoutb, idx0, idx1, g0, g1, tok_slot, out);
}

// Round 12
// 355.577 us; speedup vs baseline: 1.0852x; 1.0207x over previous
//
#include <hip/hip_runtime.h>
#include <math.h>

// ---------------- problem constants ----------------
#define TSEQ 2048
#define DD   512
#define NH   8
#define HSZ  64
#define NE   8
#define NTOK 8192    // B*T
#define CAPK 2048
#define FF   2048    // 4*D

typedef __bf16 bf16x8 __attribute__((ext_vector_type(8)));
typedef float  f32x4  __attribute__((ext_vector_type(4)));
typedef unsigned int u32;
typedef u32 u32x2 __attribute__((ext_vector_type(2)));
typedef short s16x4 __attribute__((ext_vector_type(4)));

#define WAITVM(N) asm volatile("s_waitcnt vmcnt(" #N ")" ::: "memory")

__device__ __forceinline__ void gload16(const void* g, void* l){
  __builtin_amdgcn_global_load_lds((const __attribute__((address_space(1))) u32*)g,
                                   (__attribute__((address_space(3))) u32*)l, 16, 0, 0);
}

__device__ __forceinline__ u32 pkbf(float a, float b){
  unsigned short ua = __builtin_bit_cast(unsigned short, (__bf16)a);
  unsigned short ub = __builtin_bit_cast(unsigned short, (__bf16)b);
  return (u32)ua | ((u32)ub << 16);
}

__device__ __forceinline__ u32 pksplit(float v){
  __bf16 hb = (__bf16)v;
  __bf16 lb = (__bf16)(v - (float)hb);
  return (u32)__builtin_bit_cast(unsigned short, hb) |
         ((u32)__builtin_bit_cast(unsigned short, lb) << 16);
}

__device__ __forceinline__ s16x4 mk4(u32 a, u32 b){
  u32x2 t; t[0] = a; t[1] = b;
  return __builtin_bit_cast(s16x4, t);
}

// ============================================================
// Threefry-2x32, key = (0, 42)
// ============================================================
__device__ __forceinline__ unsigned rotl32(unsigned x, int r){ return (x<<r)|(x>>(32-r)); }

__device__ __forceinline__ void threefry2x32(unsigned c0, unsigned c1, unsigned &o0, unsigned &o1){
  const unsigned k0 = 0u, k1 = 42u;
  const unsigned k2 = k0 ^ k1 ^ 0x1BD11BDAu;
  unsigned x0 = c0 + k0, x1 = c1 + k1;
#define TFR(rot) { x0 += x1; x1 = rotl32(x1, rot); x1 ^= x0; }
  TFR(13) TFR(15) TFR(26) TFR(6)   x0 += k1; x1 += k2 + 1u;
  TFR(17) TFR(29) TFR(16) TFR(24)  x0 += k2; x1 += k0 + 2u;
  TFR(13) TFR(15) TFR(26) TFR(6)   x0 += k0; x1 += k1 + 3u;
  TFR(17) TFR(29) TFR(16) TFR(24)  x0 += k1; x1 += k2 + 4u;
  TFR(13) TFR(15) TFR(26) TFR(6)   x0 += k2; x1 += k0 + 5u;
#undef TFR
  o0 = x0; o1 = x1;
}

__device__ __forceinline__ float erfinv_f(float x){
  float w = -log1pf(-x*x);
  float p;
  if (w < 5.0f){
    w -= 2.5f;
    p = 2.81022636e-08f;
    p = fmaf(p,w, 3.43273939e-07f);
    p = fmaf(p,w,-3.5233877e-06f);
    p = fmaf(p,w,-4.39150654e-06f);
    p = fmaf(p,w, 0.00021858087f);
    p = fmaf(p,w,-0.00125372503f);
    p = fmaf(p,w,-0.00417768164f);
    p = fmaf(p,w, 0.246640727f);
    p = fmaf(p,w, 1.50140941f);
  } else {
    w = sqrtf(w) - 3.0f;
    p = -0.000200214257f;
    p = fmaf(p,w, 0.000100950558f);
    p = fmaf(p,w, 0.00134934322f);
    p = fmaf(p,w,-0.00367342844f);
    p = fmaf(p,w, 0.00573950773f);
    p = fmaf(p,w,-0.0076224613f);
    p = fmaf(p,w, 0.00943887047f);
    p = fmaf(p,w, 1.00167406f);
    p = fmaf(p,w, 2.83297682f);
  }
  return p * x;
}

// ============================================================
// Merged prep: LN1->hi/lo bf16 (blk<2048), pack QKV W (2048..2239),
// transpose+split Wo (2240..2303)
// ============================================================
__global__ __launch_bounds__(256) void prep_kernel(
    const float* __restrict__ x, const float* __restrict__ ln1g, const float* __restrict__ ln1b,
    __bf16* __restrict__ h1hi, __bf16* __restrict__ h1lo,
    const float* __restrict__ Wq, const float* __restrict__ Wk, const float* __restrict__ Wv,
    __bf16* __restrict__ Bqh, __bf16* __restrict__ Bql,
    const float* __restrict__ Wo, __bf16* __restrict__ WoTh, __bf16* __restrict__ WoTl)
{
  __shared__ float t[64][65];
  int blk = blockIdx.x;
  int tid = threadIdx.x;
  if (blk < 2048){
    int row  = blk*4 + (tid >> 6);
    int lane = tid & 63;
    const float* xr = x + (size_t)row*DD;
    float4 a = *(const float4*)(xr + lane*4);
    float4 c = *(const float4*)(xr + 256 + lane*4);
    float s  = a.x+a.y+a.z+a.w + c.x+c.y+c.z+c.w;
    float ss = a.x*a.x+a.y*a.y+a.z*a.z+a.w*a.w + c.x*c.x+c.y*c.y+c.z*c.z+c.w*c.w;
    #pragma unroll
    for (int off = 32; off; off >>= 1){ s += __shfl_xor(s, off); ss += __shfl_xor(ss, off); }
    float m   = s * (1.0f/DD);
    float var = ss * (1.0f/DD) - m*m;
    float r   = 1.0f / sqrtf(var + 1e-5f);
    float4 g1 = *(const float4*)(ln1g + lane*4);
    float4 b1 = *(const float4*)(ln1b + lane*4);
    float4 g2 = *(const float4*)(ln1g + 256 + lane*4);
    float4 b2 = *(const float4*)(ln1b + 256 + lane*4);
    float f1[4], f2[4];
    f1[0]=(a.x-m)*r*g1.x+b1.x; f1[1]=(a.y-m)*r*g1.y+b1.y; f1[2]=(a.z-m)*r*g1.z+b1.z; f1[3]=(a.w-m)*r*g1.w+b1.w;
    f2[0]=(c.x-m)*r*g2.x+b2.x; f2[1]=(c.y-m)*r*g2.y+b2.y; f2[2]=(c.z-m)*r*g2.z+b2.z; f2[3]=(c.w-m)*r*g2.w+b2.w;
    __bf16 h1v[4] __attribute__((aligned(8))), l1v[4] __attribute__((aligned(8)));
    __bf16 h2v[4] __attribute__((aligned(8))), l2v[4] __attribute__((aligned(8)));
    #pragma unroll
    for (int j = 0; j < 4; ++j){
      __bf16 hb = (__bf16)f1[j]; h1v[j]=hb; l1v[j]=(__bf16)(f1[j]-(float)hb);
      __bf16 hc = (__bf16)f2[j]; h2v[j]=hc; l2v[j]=(__bf16)(f2[j]-(float)hc);
    }
    size_t base = (size_t)row*DD + lane*4;
    *(uint2*)(h1hi + base)       = *(const uint2*)h1v;
    *(uint2*)(h1lo + base)       = *(const uint2*)l1v;
    *(uint2*)(h1hi + base + 256) = *(const uint2*)h2v;
    *(uint2*)(h1lo + base + 256) = *(const uint2*)l2v;
  } else if (blk < 2240){
    int bx = blk - 2048;
    int kt = (bx & 7) * 64;
    int z  = bx >> 3;
    int sel = z >> 3, hh = z & 7;
    const float* W = (sel==0 ? Wq : (sel==1 ? Wk : Wv)) + (size_t)hh*DD*HSZ;
    int r = tid>>2, c0 = (tid&3)*16;
    #pragma unroll
    for (int j = 0; j < 16; j += 4){
      float4 v = *(const float4*)&W[(size_t)(kt+r)*HSZ + c0 + j];
      t[r][c0+j]=v.x; t[r][c0+j+1]=v.y; t[r][c0+j+2]=v.z; t[r][c0+j+3]=v.w;
    }
    __syncthreads();
    __bf16 hb[16] __attribute__((aligned(32)));
    __bf16 lb[16] __attribute__((aligned(32)));
    #pragma unroll
    for (int j = 0; j < 16; ++j){
      float f = t[c0+j][r];
      __bf16 h = (__bf16)f; hb[j]=h; lb[j]=(__bf16)(f-(float)h);
    }
    size_t off = (size_t)(z*64 + r)*512 + kt + c0;
    *(uint4*)(Bqh+off) = ((const uint4*)hb)[0]; *(uint4*)(Bqh+off+8) = ((const uint4*)hb)[1];
    *(uint4*)(Bql+off) = ((const uint4*)lb)[0]; *(uint4*)(Bql+off+8) = ((const uint4*)lb)[1];
  } else {
    int bx = blk - 2240;
    int nt = (bx & 7) * 64, mt = (bx >> 3) * 64;
    int r = tid>>2, c0 = (tid&3)*16;
    #pragma unroll
    for (int j = 0; j < 16; j += 4){
      float4 v = *(const float4*)&Wo[(size_t)(mt+r)*DD + nt + c0 + j];
      t[r][c0+j]=v.x; t[r][c0+j+1]=v.y; t[r][c0+j+2]=v.z; t[r][c0+j+3]=v.w;
    }
    __syncthreads();
    __bf16 hb[16] __attribute__((aligned(32)));
    __bf16 lb[16] __attribute__((aligned(32)));
    #pragma unroll
    for (int j = 0; j < 16; ++j){
      float f = t[c0+j][r];
      __bf16 h = (__bf16)f; hb[j]=h; lb[j]=(__bf16)(f-(float)h);
    }
    size_t off = (size_t)(nt + r)*DD + mt + c0;
    *(uint4*)(WoTh+off) = ((const uint4*)hb)[0]; *(uint4*)(WoTh+off+8) = ((const uint4*)hb)[1];
    *(uint4*)(WoTl+off) = ((const uint4*)lb)[0]; *(uint4*)(WoTl+off+8) = ((const uint4*)lb)[1];
  }
}

// ============================================================
// bf16x3 split-precision MFMA GEMM, 2-phase counted-vmcnt,
// 1-D XCD-swizzled grid.
// MODE 0: C f32 = A@B^T + bias + res    (Wo)
// MODE 1: QKV epilogue via LDS
// ============================================================
template<int MODE, int NN>
__global__ __launch_bounds__(256) void gemm_mfma3(
    const __bf16* __restrict__ Ahi, const __bf16* __restrict__ Alo,
    const __bf16* __restrict__ Bhi, const __bf16* __restrict__ Blo,
    const float* __restrict__ bias, const float* __restrict__ res, float* __restrict__ C,
    __bf16* __restrict__ qh, __bf16* __restrict__ ql,
    __bf16* __restrict__ kh, __bf16* __restrict__ kl,
    __bf16* __restrict__ vth, __bf16* __restrict__ vtl,
    int M, int N, int K)
{
  __shared__ __align__(16) char smem[65536];
  __bf16* AsH = (__bf16*)smem;            // [2][4096]
  __bf16* AsL = (__bf16*)(smem + 16384);
  __bf16* BsH = (__bf16*)(smem + 32768);
  __bf16* BsL = (__bf16*)(smem + 49152);

  int flat  = blockIdx.x;
  int chunk = flat / (8*NN);
  int rem   = flat % (8*NN);
  int mloc  = rem & 7;
  int nn    = rem >> 3;
  int m0 = (chunk*8 + mloc)*128;
  int n0 = nn*128;

  int tid = threadIdx.x;
  int w = tid>>6, l = tid&63;
  int wm = w>>1, wn = w&1;
  int srow = w*32 + (l>>2);
  int skb  = (l&3)<<4;
  const char* agh = (const char*)(Ahi + (size_t)(m0+srow)*K) + skb;
  const char* agl = (const char*)(Alo + (size_t)(m0+srow)*K) + skb;
  const char* bgh = (const char*)(Bhi + (size_t)(n0+srow)*K) + skb;
  const char* bgl = (const char*)(Blo + (size_t)(n0+srow)*K) + skb;
  size_t r16 = (size_t)16*K*sizeof(__bf16);

  f32x4 acc[4][4] = {};
  int rl = l & 15, kh_ = l >> 4;
  const __bf16* abh = AsH + (wm*64 + rl)*32 + kh_*8;
  const __bf16* abl = AsL + (wm*64 + rl)*32 + kh_*8;
  const __bf16* bbh = BsH + (wn*64 + rl)*32 + kh_*8;
  const __bf16* bbl = BsL + (wn*64 + rl)*32 + kh_*8;

  auto STAGE = [&](int bb, int kt){
    size_t o = (size_t)kt*64;
    gload16(agh+o,     AsH + bb*4096 + w*1024);
    gload16(agh+o+r16, AsH + bb*4096 + w*1024+512);
    gload16(agl+o,     AsL + bb*4096 + w*1024);
    gload16(agl+o+r16, AsL + bb*4096 + w*1024+512);
    gload16(bgh+o,     BsH + bb*4096 + w*1024);
    gload16(bgh+o+r16, BsH + bb*4096 + w*1024+512);
    gload16(bgl+o,     BsL + bb*4096 + w*1024);
    gload16(bgl+o+r16, BsL + bb*4096 + w*1024+512);
  };

  int nkt = K >> 5;
  STAGE(0, 0);
  for (int kt = 0; kt < nkt; ++kt){
    int bb = kt & 1;
    if (kt + 1 < nkt){ STAGE(bb^1, kt+1); WAITVM(8); }
    else             { WAITVM(0); }
    __builtin_amdgcn_s_barrier();
    bf16x8 afh[4], afl[4], bfh[4], bfl[4];
    #pragma unroll
    for (int i = 0; i < 4; ++i){
      afh[i] = *(const bf16x8*)(abh + bb*4096 + i*512);
      afl[i] = *(const bf16x8*)(abl + bb*4096 + i*512);
      bfh[i] = *(const bf16x8*)(bbh + bb*4096 + i*512);
      bfl[i] = *(const bf16x8*)(bbl + bb*4096 + i*512);
    }
    #pragma unroll
    for (int fm = 0; fm < 4; ++fm)
      #pragma unroll
      for (int fn = 0; fn < 4; ++fn){
        acc[fm][fn] = __builtin_amdgcn_mfma_f32_16x16x32_bf16(afh[fm], bfl[fn], acc[fm][fn], 0, 0, 0);
        acc[fm][fn] = __builtin_amdgcn_mfma_f32_16x16x32_bf16(afl[fm], bfh[fn], acc[fm][fn], 0, 0, 0);
        acc[fm][fn] = __builtin_amdgcn_mfma_f32_16x16x32_bf16(afh[fm], bfh[fn], acc[fm][fn], 0, 0, 0);
      }
    __builtin_amdgcn_s_barrier();
  }

  int ccol = l & 15, cr = (l >> 4) * 4;
  if (MODE == 0){
    #pragma unroll
    for (int fn = 0; fn < 4; ++fn){
      int n = n0 + wn*64 + fn*16 + ccol;
      float bv = bias[n];
      #pragma unroll
      for (int fm = 0; fm < 4; ++fm){
        int mb = m0 + wm*64 + fm*16 + cr;
        #pragma unroll
        for (int r = 0; r < 4; ++r){
          float v = acc[fm][fn][r] + bv + res[(size_t)(mb+r)*N + n];
          C[(size_t)(mb+r)*N + n] = v;
        }
      }
    }
  } else {
    u32 (*eps)[132] = (u32(*)[132])smem;
    int sel = n0 >> 9;                 // 0=Q,1=K,2=V
    int b   = m0 >> 11;
    int tb  = m0 & 2047;
    int dbase = n0 & 511;
    const float qsc = 0.04419417382415922f * 1.4426950408889634f;  // D^-0.5 * log2(e)
    float sc = (sel == 0) ? qsc : 1.0f;
    #pragma unroll
    for (int p = 0; p < 2; ++p){
      __syncthreads();
      if (sel < 2){
        if (wm == p){
          #pragma unroll
          for (int fm = 0; fm < 4; ++fm)
            #pragma unroll
            for (int fn = 0; fn < 4; ++fn)
              #pragma unroll
              for (int r = 0; r < 4; ++r)
                eps[fm*16 + cr + r][wn*64 + fn*16 + ccol] = pksplit(acc[fm][fn][r] * sc);
        }
        __syncthreads();
        int row = tid >> 2, q4 = tid & 3;
        int hh = (dbase >> 6) + (q4 >> 1);
        int e0 = (q4 & 1) * 32;
        const u32* src = &eps[row][q4*32];
        __bf16 hbuf[32] __attribute__((aligned(16)));
        __bf16 lbuf[32] __attribute__((aligned(16)));
        #pragma unroll
        for (int j = 0; j < 32; ++j){
          u32 pk = src[j];
          hbuf[j] = __builtin_bit_cast(__bf16, (unsigned short)(pk & 0xffffu));
          lbuf[j] = __builtin_bit_cast(__bf16, (unsigned short)(pk >> 16));
        }
        size_t off = ((size_t)(b*8 + hh)*TSEQ + tb + p*64 + row)*64 + e0;
        __bf16* dh = sel ? kh : qh;
        __bf16* dl = sel ? kl : ql;
        #pragma unroll
        for (int j = 0; j < 4; ++j){
          *(uint4*)(dh + off + j*8) = ((const uint4*)hbuf)[j];
          *(uint4*)(dl + off + j*8) = ((const uint4*)lbuf)[j];
        }
      } else {
        if (wn == p){
          #pragma unroll
          for (int fn = 0; fn < 4; ++fn)
            #pragma unroll
            for (int fm = 0; fm < 4; ++fm){
              u32 pk4[4] __attribute__((aligned(16)));
              #pragma unroll
              for (int r = 0; r < 4; ++r)
                pk4[r] = pksplit(acc[fm][fn][r]);
              *(uint4*)&eps[fn*16 + ccol][wm*64 + fm*16 + cr] = *(const uint4*)pk4;
            }
        }
        __syncthreads();
        int col = tid >> 2, tq = tid & 3;
        int d = dbase + p*64 + col;
        int hh = d >> 6, e = d & 63;
        const u32* src = &eps[col][tq*32];
        __bf16 hbuf[32] __attribute__((aligned(16)));
        __bf16 lbuf[32] __attribute__((aligned(16)));
        #pragma unroll
        for (int j = 0; j < 32; ++j){
          u32 pk = src[j];
          hbuf[j] = __builtin_bit_cast(__bf16, (unsigned short)(pk & 0xffffu));
          lbuf[j] = __builtin_bit_cast(__bf16, (unsigned short)(pk >> 16));
        }
        size_t off = ((size_t)(b*8 + hh)*64 + e)*TSEQ + tb + tq*32;
        #pragma unroll
        for (int j = 0; j < 4; ++j){
          *(uint4*)(vth + off + j*8) = ((const uint4*)hbuf)[j];
          *(uint4*)(vtl + off + j*8) = ((const uint4*)lbuf)[j];
        }
      }
    }
  }
}

// ============================================================
// bf16 MFMA GEMM (experts), 3-buffer depth-2 prefetch pipeline,
// XCD-local experts, optional gather-indirect A.
// ============================================================
template<int STORE_BF16, int RELU, int GATHER, int LOGN, int EBITS>
__global__ __launch_bounds__(256) void gemm_mfma(
    const __bf16* __restrict__ A, const __bf16* __restrict__ Bt,
    const float* __restrict__ bias, void* __restrict__ Cv,
    const int* __restrict__ idxb, int M, int N, int K)
{
  __shared__ __bf16 Asl[3][4096];
  __shared__ __bf16 Bsl[3][4096];
  int flat = blockIdx.x;
  int e = flat & ((1<<EBITS)-1);
  int tile = flat >> EBITS;
  int n0 = (tile & ((1<<LOGN)-1)) * 128;
  int m0 = (tile >> LOGN) * 128;
  const __bf16* Be = Bt + (size_t)e*N*K;
  const float*  be = bias + (size_t)e*N;
  int tid = threadIdx.x;
  int w = tid>>6, l = tid&63;
  int wm = w>>1, wn = w&1;
  int srow = w*32 + (l>>2);
  int skb  = (l&3)<<4;
  const char* ag;
  if (GATHER){
    int tok = idxb[e*CAPK + m0 + srow];
    ag = (const char*)(A + (size_t)tok*K) + skb;
  } else {
    ag = (const char*)(A + (size_t)e*M*K + (size_t)(m0 + srow)*K) + skb;
  }
  const char* bg = (const char*)(Be + (size_t)(n0 + srow)*K) + skb;
  size_t r16;
  if (GATHER){
    int tok2 = idxb[e*CAPK + m0 + srow + 16];
    r16 = (size_t)((const char*)(A + (size_t)tok2*K) + skb - ag);
  } else {
    r16 = (size_t)16*K*sizeof(__bf16);
  }

  f32x4 acc[4][4] = {};
  int rl = l & 15, kh = l >> 4;
  const __bf16* abase = &Asl[0][(wm*64 + rl)*32 + kh*8];
  const __bf16* bbase = &Bsl[0][(wn*64 + rl)*32 + kh*8];

  size_t br16 = (size_t)16*K*sizeof(__bf16);
  auto STAGE = [&](int bb, int kt){
    size_t o = (size_t)kt*64;
    gload16(ag+o,      &Asl[bb][w*1024]);
    gload16(ag+o+r16,  &Asl[bb][w*1024+512]);
    gload16(bg+o,      &Bsl[bb][w*1024]);
    gload16(bg+o+br16, &Bsl[bb][w*1024+512]);
  };

  int nkt = K >> 5;          // >= 16 always here
  STAGE(0, 0);
  STAGE(1, 1);
  int bb = 0, st = 2;        // current buf, stage-target buf
  for (int kt = 0; kt < nkt; ++kt){
    if (kt + 2 < nkt){ STAGE(st, kt+2); WAITVM(8); }
    else if (kt + 1 < nkt){ WAITVM(4); }
    else { WAITVM(0); }
    __builtin_amdgcn_s_barrier();
    bf16x8 af[4], bf[4];
    #pragma unroll
    for (int i = 0; i < 4; ++i){
      af[i] = *(const bf16x8*)(abase + bb*4096 + i*512);
      bf[i] = *(const bf16x8*)(bbase + bb*4096 + i*512);
    }
    #pragma unroll
    for (int fm = 0; fm < 4; ++fm)
      #pragma unroll
      for (int fn = 0; fn < 4; ++fn)
        acc[fm][fn] = __builtin_amdgcn_mfma_f32_16x16x32_bf16(af[fm], bf[fn], acc[fm][fn], 0, 0, 0);
    __builtin_amdgcn_s_barrier();
    bb = (bb == 2) ? 0 : bb + 1;
    st = (st == 2) ? 0 : st + 1;
  }

  int ccol = l & 15, cr = (l >> 4) * 4;
  char* Ce = (char*)Cv + (size_t)e*M*N*(STORE_BF16 ? 2 : 4);
  #pragma unroll
  for (int fn = 0; fn < 4; ++fn){
    int n = n0 + wn*64 + fn*16 + ccol;
    float bv = be[n];
    #pragma unroll
    for (int fm = 0; fm < 4; ++fm){
      int mb = m0 + wm*64 + fm*16 + cr;
      #pragma unroll
      for (int r = 0; r < 4; ++r){
        float v = acc[fm][fn][r] + bv;
        if (RELU) v = fmaxf(v, 0.f);
        if (STORE_BF16) ((__bf16*)Ce)[(size_t)(mb+r)*N + n] = (__bf16)v;
        else            ((float*)Ce)[(size_t)(mb+r)*N + n] = v;
      }
    }
  }
}

// ============================================================
// Merged: transpose+convert W1,W2 (id<512) + capacity route_scan (id==512)
// grid (513, 1, 8)
// ============================================================
__global__ __launch_bounds__(256) void transp_scan(const float* __restrict__ W1,
    const float* __restrict__ W2, __bf16* __restrict__ d1, __bf16* __restrict__ d2,
    const int* __restrict__ idx0, const int* __restrict__ idx1,
    int* __restrict__ idx_buf, int* __restrict__ tok_slot)
{
  __shared__ __bf16 t[64][72];
  __shared__ int ps[256];
  int e = blockIdx.z;
  int id = blockIdx.x;
  int tid = threadIdx.x;
  if (id == 512){
    // route_scan for expert e
    for (int i = tid; i < CAPK; i += 256) idx_buf[e*CAPK + i] = 0;
    __syncthreads();
    int base = tid * 32;
    int cnt = 0;
    for (int j = 0; j < 32; ++j){ int tt = base + j; cnt += (idx0[tt]==e || idx1[tt]==e) ? 1 : 0; }
    ps[tid] = cnt; __syncthreads();
    for (int off = 1; off < 256; off <<= 1){
      int add = (tid >= off) ? ps[tid - off] : 0;
      __syncthreads();
      ps[tid] += add;
      __syncthreads();
    }
    int slot = ps[tid] - cnt;
    for (int j = 0; j < 32; ++j){
      int tt = base + j;
      int k = (idx0[tt]==e) ? 0 : ((idx1[tt]==e) ? 1 : -1);
      if (k >= 0){
        if (slot < CAPK){ idx_buf[e*CAPK + slot] = tt; tok_slot[tt*2 + k] = slot; }
        else            { tok_slot[tt*2 + k] = -1; }
        slot++;
      }
    }
    return;
  }
  const float* s; __bf16* d; int Ms, Ns, mt, nt;
  if (id < 256){ s = W1; d = d1; Ms = DD; Ns = FF; nt = (id&31)*64; mt = (id>>5)*64; }
  else { int i2 = id-256; s = W2; d = d2; Ms = FF; Ns = DD; nt = (i2&7)*64; mt = (i2>>3)*64; }
  s += (size_t)e*Ms*Ns;
  d += (size_t)e*Ms*Ns;
  int r = tid>>2, c0 = (tid&3)*16;
  #pragma unroll
  for (int j = 0; j < 16; j += 4){
    float4 v = *(const float4*)&s[(size_t)(mt+r)*Ns + nt + c0 + j];
    t[r][c0+j]   = (__bf16)v.x; t[r][c0+j+1] = (__bf16)v.y;
    t[r][c0+j+2] = (__bf16)v.z; t[r][c0+j+3] = (__bf16)v.w;
  }
  __syncthreads();
  __bf16 tmp[16] __attribute__((aligned(32)));
  #pragma unroll
  for (int j = 0; j < 16; ++j) tmp[j] = t[c0+j][r];
  uint4* dp = (uint4*)&d[(size_t)(nt+r)*Ms + mt + c0];
  dp[0] = ((const uint4*)tmp)[0];
  dp[1] = ((const uint4*)tmp)[1];
}

// ============================================================
// bf16x3 MFMA flash attention, KVBLK=128, dynamic LDS 128KB.
// Q/K/V pre-split bf16 hi/lo (Q pre-scaled, exp2 domain).
// defer-max THR=8 (T13).
// ============================================================
__global__ __launch_bounds__(512) void attn_mfma(
    const __bf16* __restrict__ qhi_g, const __bf16* __restrict__ qlo_g,
    const __bf16* __restrict__ khi_g, const __bf16* __restrict__ klo_g,
    const __bf16* __restrict__ vthi_g, const __bf16* __restrict__ vtlo_g,
    __bf16* __restrict__ ahi, __bf16* __restrict__ alo)
{
  extern __shared__ __align__(16) char ldsbuf[];
  int bh = blockIdx.x;
  int qtA = blockIdx.y, qtB = 15 - qtA;      // 128-row q-tiles
  int b = bh >> 3, h = bh & 7;
  int tid = threadIdx.x;
  int w = tid >> 6, l = tid & 63;
  int g = l >> 4, r = l & 15;

  int qb[2]; qb[0] = qtA*128 + w*16; qb[1] = qtB*128 + (7-w)*16;
  int kdiag[2]; kdiag[0] = qtA; kdiag[1] = qtB;

  bf16x8 qhi[2][2], qlo[2][2];
  #pragma unroll
  for (int qf = 0; qf < 2; ++qf)
    #pragma unroll
    for (int ks = 0; ks < 2; ++ks){
      size_t qoff = ((size_t)bh*TSEQ + qb[qf] + r)*64 + ks*32 + g*8;
      qhi[qf][ks] = *(const bf16x8*)(qhi_g + qoff);
      qlo[qf][ks] = *(const bf16x8*)(qlo_g + qoff);
    }

  f32x4 ot[4][2] = {};
  float m_r[2] = {-INFINITY, -INFINITY};
  float l_r[2] = {0.f, 0.f};

  int nkt = qtB + 1;
  size_t kbase = (size_t)bh*TSEQ*64;
  size_t vbase = (size_t)bh*64*TSEQ;

  auto STAGE = [&](int buf, int kt){
    int row = tid >> 3, cc = tid & 7;
    char* base = ldsbuf + buf*65536 + (w << 10);
    #pragma unroll
    for (int p = 0; p < 2; ++p){
      int krow = p*64 + row;
      int ksw = (cc ^ (krow & 7)) * 8;
      gload16(khi_g + kbase + (size_t)(kt*128 + krow)*64 + ksw, base + p*8192);
      gload16(klo_g + kbase + (size_t)(kt*128 + krow)*64 + ksw, base + 16384 + p*8192);
      int vch = p*8 + cc;
      int vsw = ((vch ^ (row & 7)) & 15) * 8;
      gload16(vthi_g + vbase + (size_t)row*TSEQ + kt*128 + vsw, base + 32768 + p*8192);
      gload16(vtlo_g + vbase + (size_t)row*TSEQ + kt*128 + vsw, base + 49152 + p*8192);
    }
  };

  STAGE(0, 0);

  for (int kt = 0; kt < nkt; ++kt){
    int buf = kt & 1;
    if (kt + 1 < nkt){ STAGE(buf ^ 1, kt + 1); WAITVM(8); }
    else             { WAITVM(0); }
    __builtin_amdgcn_s_barrier();

    bool act[2];
    act[0] = (kt <= kdiag[0]);
    act[1] = true;

    const char* K0 = ldsbuf + buf*65536;
    const char* K1 = K0 + 16384;
    const char* V0 = K0 + 32768;
    const char* V1 = K0 + 49152;

    // ---- S^T = K · Q^T (bf16x3), 8 key-frags ----
    f32x4 s[8][2] = {};
    #pragma unroll
    for (int kf = 0; kf < 8; ++kf){
      int rowk = kf*16 + r;
      int rsw = (rowk & 7) << 4;
      #pragma unroll
      for (int ks = 0; ks < 2; ++ks){
        int off = rowk*128 + ((((ks*4 + g) << 4)) ^ rsw);
        bf16x8 khf = *(const bf16x8*)(K0 + off);
        bf16x8 klf = *(const bf16x8*)(K1 + off);
        #pragma unroll
        for (int qf = 0; qf < 2; ++qf){
          if (act[qf]){
            s[kf][qf] = __builtin_amdgcn_mfma_f32_16x16x32_bf16(khf, qlo[qf][ks], s[kf][qf], 0,0,0);
            s[kf][qf] = __builtin_amdgcn_mfma_f32_16x16x32_bf16(klf, qhi[qf][ks], s[kf][qf], 0,0,0);
            s[kf][qf] = __builtin_amdgcn_mfma_f32_16x16x32_bf16(khf, qhi[qf][ks], s[kf][qf], 0,0,0);
          }
        }
      }
    }

    // ---- mask (diag tile) + online softmax (exp2, defer-max THR=8) ----
    #pragma unroll
    for (int qf = 0; qf < 2; ++qf){
      if (act[qf]){
        int q = qb[qf] + r;
        float mx = -INFINITY;
        if (kt == kdiag[qf]){
          #pragma unroll
          for (int kf = 0; kf < 8; ++kf)
            #pragma unroll
            for (int e = 0; e < 4; ++e){
              int key = kt*128 + kf*16 + g*4 + e;
              float sv = (key <= q) ? s[kf][qf][e] : -INFINITY;
              s[kf][qf][e] = sv;
              mx = fmaxf(mx, sv);
            }
        } else {
          #pragma unroll
          for (int kf = 0; kf < 8; ++kf)
            #pragma unroll
            for (int e = 0; e < 4; ++e)
              mx = fmaxf(mx, s[kf][qf][e]);
        }
        mx = fmaxf(mx, __shfl_xor(mx, 16));
        mx = fmaxf(mx, __shfl_xor(mx, 32));
        if (__any(mx > m_r[qf] + 8.0f)){          // defer-max (T13)
          float mn = fmaxf(m_r[qf], mx);
          float fj = exp2f(m_r[qf] - mn);
          m_r[qf] = mn;
          l_r[qf] *= fj;
          #pragma unroll
          for (int ef = 0; ef < 4; ++ef)
            #pragma unroll
            for (int e = 0; e < 4; ++e)
              ot[ef][qf][e] *= fj;
        }
        float ts = 0.f;
        #pragma unroll
        for (int kf = 0; kf < 8; ++kf)
          #pragma unroll
          for (int e = 0; e < 4; ++e){
            float pv = exp2f(s[kf][qf][e] - m_r[qf]);
            s[kf][qf][e] = pv; ts += pv;
          }
        ts += __shfl_xor(ts, 16); ts += __shfl_xor(ts, 32);
        l_r[qf] += ts;
      }
    }

    // ---- O^T += V^T · P^T via K=16 MFMA; P frags packed in-loop ----
    #pragma unroll
    for (int kf = 0; kf < 8; ++kf){
      u32 PH[2][2], PL[2][2];
      #pragma unroll
      for (int qf = 0; qf < 2; ++qf){
        if (act[qf]){
          float p0 = s[kf][qf][0], p1 = s[kf][qf][1], p2 = s[kf][qf][2], p3 = s[kf][qf][3];
          __bf16 h0=(__bf16)p0, h1=(__bf16)p1, h2=(__bf16)p2, h3=(__bf16)p3;
          PH[qf][0] = pkbf(p0, p1);
          PH[qf][1] = pkbf(p2, p3);
          PL[qf][0] = pkbf(p0-(float)h0, p1-(float)h1);
          PL[qf][1] = pkbf(p2-(float)h2, p3-(float)h3);
        }
      }
      int chunk = 2*kf + (g>>1);
      int pb = (chunk >> 3) << 13;
      int cl = chunk & 7;
      #pragma unroll
      for (int ef = 0; ef < 4; ++ef){
        int rowv = ef*16 + r;
        int off = pb + rowv*128 + ((cl ^ (rowv & 7)) << 4) + (g&1)*8;
        s16x4 vh = *(const s16x4*)(V0 + off);
        s16x4 vl = *(const s16x4*)(V1 + off);
        #pragma unroll
        for (int qf = 0; qf < 2; ++qf){
          if (act[qf]){
            s16x4 ph = mk4(PH[qf][0], PH[qf][1]);
            s16x4 pl = mk4(PL[qf][0], PL[qf][1]);
            ot[ef][qf] = __builtin_amdgcn_mfma_f32_16x16x16bf16_1k(vh, pl, ot[ef][qf], 0,0,0);
            ot[ef][qf] = __builtin_amdgcn_mfma_f32_16x16x16bf16_1k(vl, ph, ot[ef][qf], 0,0,0);
            ot[ef][qf] = __builtin_amdgcn_mfma_f32_16x16x16bf16_1k(vh, ph, ot[ef][qf], 0,0,0);
          }
        }
      }
    }
    __builtin_amdgcn_s_barrier();
  }

  // ---- epilogue ----
  float* Osh = (float*)ldsbuf;   // [128][68]
  #pragma unroll
  for (int qf = 0; qf < 2; ++qf){
    float inv = 1.0f / l_r[qf];
    int qloc = (qf ? (7-w) : w)*16 + r;
    #pragma unroll
    for (int ef = 0; ef < 4; ++ef)
      #pragma unroll
      for (int e = 0; e < 4; ++e)
        Osh[qloc*68 + ef*16 + g*4 + e] = ot[ef][qf][e] * inv;
    __syncthreads();
    {
      int qt = qf ? qtB : qtA;
      int q = tid >> 2, e0 = (tid & 3)*16;
      const float* srow = Osh + q*68 + e0;
      size_t base = ((size_t)(b*TSEQ + qt*128 + q))*DD + h*64 + e0;
      #pragma unroll
      for (int j = 0; j < 4; ++j){
        float4 v = *(const float4*)(srow + j*4);
        float f[4] = {v.x, v.y, v.z, v.w};
        __bf16 hb[4] __attribute__((aligned(8)));
        __bf16 lb[4] __attribute__((aligned(8)));
        #pragma unroll
        for (int q2 = 0; q2 < 4; ++q2){
          __bf16 h2b = (__bf16)f[q2];
          hb[q2] = h2b; lb[q2] = (__bf16)(f[q2] - (float)h2b);
        }
        *(uint2*)(ahi + base + j*4) = *(const uint2*)hb;
        *(uint2*)(alo + base + j*4) = *(const uint2*)lb;
      }
    }
    __syncthreads();
  }
}

// ============================================================
// Fused LN2 + Router
// ============================================================
__global__ __launch_bounds__(256) void routerln_kernel(const float* __restrict__ x1,
    const float* __restrict__ gw, const float* __restrict__ bw,
    const float* __restrict__ Wg, const float* __restrict__ bg,
    const float* __restrict__ Wn, const float* __restrict__ bn,
    __bf16* __restrict__ h2b,
    int* __restrict__ idx0, int* __restrict__ idx1,
    float* __restrict__ g0, float* __restrict__ g1)
{
  int wid = threadIdx.x >> 6, lane = threadIdx.x & 63;
  int tok = blockIdx.x*4 + wid;
  const float* xr = x1 + (size_t)tok*DD;
  float4 a = *(const float4*)(xr + lane*4);
  float4 c = *(const float4*)(xr + 256 + lane*4);
  float s  = a.x+a.y+a.z+a.w + c.x+c.y+c.z+c.w;
  float ss = a.x*a.x+a.y*a.y+a.z*a.z+a.w*a.w + c.x*c.x+c.y*c.y+c.z*c.z+c.w*c.w;
  #pragma unroll
  for (int off = 32; off; off >>= 1){ s += __shfl_xor(s, off); ss += __shfl_xor(ss, off); }
  float m   = s * (1.0f/DD);
  float var = ss * (1.0f/DD) - m*m;
  float rr  = 1.0f / sqrtf(var + 1e-5f);
  float4 g1v = *(const float4*)(gw + lane*4);
  float4 b1v = *(const float4*)(bw + lane*4);
  float4 g2v = *(const float4*)(gw + 256 + lane*4);
  float4 b2v = *(const float4*)(bw + 256 + lane*4);
  float f1[4], f2[4];
  f1[0]=(a.x-m)*rr*g1v.x+b1v.x; f1[1]=(a.y-m)*rr*g1v.y+b1v.y; f1[2]=(a.z-m)*rr*g1v.z+b1v.z; f1[3]=(a.w-m)*rr*g1v.w+b1v.w;
  f2[0]=(c.x-m)*rr*g2v.x+b2v.x; f2[1]=(c.y-m)*rr*g2v.y+b2v.y; f2[2]=(c.z-m)*rr*g2v.z+b2v.z; f2[3]=(c.w-m)*rr*g2v.w+b2v.w;
  {
    __bf16 h1v[4] __attribute__((aligned(8)));
    __bf16 h2v[4] __attribute__((aligned(8)));
    #pragma unroll
    for (int j = 0; j < 4; ++j){ h1v[j] = (__bf16)f1[j]; h2v[j] = (__bf16)f2[j]; }
    size_t base = (size_t)tok*DD + lane*4;
    *(uint2*)(h2b + base)       = *(const uint2*)h1v;
    *(uint2*)(h2b + base + 256) = *(const uint2*)h2v;
  }
  float ag[8] = {0,0,0,0,0,0,0,0}, an[8] = {0,0,0,0,0,0,0,0};
  int d1 = lane*4, d2 = 256 + lane*4;
  #pragma unroll
  for (int j = 0; j < 4; ++j){
    const float* wg1 = Wg + (size_t)(d1+j)*8;
    const float* wn1 = Wn + (size_t)(d1+j)*8;
    const float* wg2 = Wg + (size_t)(d2+j)*8;
    const float* wn2 = Wn + (size_t)(d2+j)*8;
    #pragma unroll
    for (int e = 0; e < 8; ++e){
      ag[e] = fmaf(f1[j], wg1[e], ag[e]); an[e] = fmaf(f1[j], wn1[e], an[e]);
      ag[e] = fmaf(f2[j], wg2[e], ag[e]); an[e] = fmaf(f2[j], wn2[e], an[e]);
    }
  }
  #pragma unroll
  for (int off = 32; off; off >>= 1){
    #pragma unroll
    for (int e = 0; e < 8; ++e){ ag[e] += __shfl_xor(ag[e], off); an[e] += __shfl_xor(an[e], off); }
  }
  __shared__ float ns[4][8];
  if (lane < 8){
    int e = lane;
    float lg = ag[e] + bg[e];
    float nl = an[e] + bn[e];
    float sp = fmaxf(nl, 0.f) + log1pf(expf(-fabsf(nl)));
    unsigned i = (unsigned)(tok*8 + e);
    unsigned r0b, r1b;
    threefry2x32(0u, i, r0b, r1b);
    unsigned bits = r0b ^ r1b;
    float f = __uint_as_float((bits >> 9) | 0x3f800000u) - 1.0f;
    float u = fmaf(f, 2.0f, -0.99999994f);
    u = fmaxf(u, -0.99999994f);
    float z = 1.41421356f * erfinv_f(u);
    ns[wid][e] = lg + z*sp;
  }
  __syncthreads();
  if (lane == 0){
    float v0 = -INFINITY; int i0 = 0;
    #pragma unroll
    for (int e = 0; e < 8; ++e){ float v = ns[wid][e]; if (v > v0){ v0 = v; i0 = e; } }
    float v1 = -INFINITY; int i1 = 0;
    #pragma unroll
    for (int e = 0; e < 8; ++e){ if (e != i0){ float v = ns[wid][e]; if (v > v1){ v1 = v; i1 = e; } } }
    float dexp = expf(v1 - v0);
    float ssum = 1.0f + dexp;
    idx0[tok] = i0; idx1[tok] = i1;
    g0[tok] = 1.0f/ssum; g1[tok] = dexp/ssum;
  }
}

// ============================================================
// Combine (eout bf16)
// ============================================================
__global__ __launch_bounds__(128) void combine_kernel(const float* __restrict__ x1,
    const __bf16* __restrict__ eout, const int* __restrict__ idx0, const int* __restrict__ idx1,
    const float* __restrict__ g0, const float* __restrict__ g1,
    const int* __restrict__ tok_slot, float* __restrict__ outp)
{
  int n = blockIdx.x, t = threadIdx.x;
  float4 acc = *(const float4*)(x1 + (size_t)n*DD + t*4);
  #pragma unroll
  for (int k = 0; k < 2; ++k){
    int s = tok_slot[n*2 + k];
    if (s >= 0){
      int e  = (k==0) ? idx0[n] : idx1[n];
      float g = (k==0) ? g0[n] : g1[n];
      __bf16 vb[4] __attribute__((aligned(8)));
      *(uint2*)vb = *(const uint2*)(eout + ((size_t)(e*CAPK + s))*DD + t*4);
      acc.x = fmaf(g, (float)vb[0], acc.x); acc.y = fmaf(g, (float)vb[1], acc.y);
      acc.z = fmaf(g, (float)vb[2], acc.z); acc.w = fmaf(g, (float)vb[3], acc.w);
    }
  }
  *(float4*)(outp + (size_t)n*DD + t*4) = acc;
}

// ============================================================
extern "C" void kernel_launch(void* const* d_in, const int* in_sizes, int n_in,
                              void* d_out, int out_size, void* d_ws, size_t ws_size,
                              hipStream_t stream)
{
  const float* x    = (const float*)d_in[0];
  const float* ln1g = (const float*)d_in[1];
  const float* ln1b = (const float*)d_in[2];
  const float* Wq   = (const float*)d_in[3];
  const float* Wk   = (const float*)d_in[4];
  const float* Wv   = (const float*)d_in[5];
  const float* Wo   = (const float*)d_in[6];
  const float* bo   = (const float*)d_in[7];
  const float* ln2g = (const float*)d_in[8];
  const float* ln2b = (const float*)d_in[9];
  const float* Wg   = (const float*)d_in[10];
  const float* bg   = (const float*)d_in[11];
  const float* Wn   = (const float*)d_in[12];
  const float* bn   = (const float*)d_in[13];
  const float* W1   = (const float*)d_in[14];
  const float* b1   = (const float*)d_in[15];
  const float* W2   = (const float*)d_in[16];
  const float* b2   = (const float*)d_in[17];
  float* out = (float*)d_out;
  char* ws = (char*)d_ws;
  const size_t MB = 1u << 20;

  (void)hipFuncSetAttribute((const void*)attn_mfma,
      hipFuncAttributeMaxDynamicSharedMemorySize, 131072);

  // workspace layout (time-aliased; peak ~145.5 MiB)
  __bf16* h1hi   = (__bf16*)(ws);             // 0..8   : LN1 hi (s1-2)
  __bf16* h1lo   = (__bf16*)(ws + 8*MB);      // 8..16  : LN1 lo
  __bf16* attnhi = (__bf16*)(ws);             // 0..8   : attn out hi (s3-4)
  __bf16* attnlo = (__bf16*)(ws + 8*MB);      // 8..16
  __bf16* h2b    = (__bf16*)(ws);             // 0..8   : LN2 out bf16 (s5-8)
  __bf16* Qhi    = (__bf16*)(ws + 16*MB);     // 16..24 (s2-3)
  __bf16* Qlo    = (__bf16*)(ws + 24*MB);     // 24..32
  __bf16* Khi    = (__bf16*)(ws + 32*MB);     // 32..40
  __bf16* Klo    = (__bf16*)(ws + 40*MB);     // 40..48
  __bf16* Vthi   = (__bf16*)(ws + 48*MB);     // 48..56
  __bf16* Vtlo   = (__bf16*)(ws + 56*MB);     // 56..64
  __bf16* W1T    = (__bf16*)(ws + 16*MB);     // 16..32 (s6-8; over Q, dead after attn)
  __bf16* W2T    = (__bf16*)(ws + 32*MB);     // 32..48 (over K, dead)
  __bf16* eoutb  = (__bf16*)(ws + 48*MB);     // 48..64 (s9-10; over V, dead)
  float*  x1     = (float*)(ws + 64*MB);      // 64..80 (s4-10)
  __bf16* Bqh    = (__bf16*)(ws + 80*MB);     // 80..81.5 (s1-2)
  __bf16* Bql    = (__bf16*)(ws + 82*MB);     // 82..83.5
  __bf16* mid    = (__bf16*)(ws + 80*MB);     // 80..144 (s8-9; Bq dead)
  __bf16* WoTh   = (__bf16*)(ws + 144*MB);    // 144..144.5 (s1-4)
  __bf16* WoTl   = (__bf16*)(ws + 144*MB + 512*1024);
  char*   smallp = ws + 145*MB;
  int*   idx0     = (int*)smallp;
  int*   idx1     = idx0 + NTOK;
  float* g0       = (float*)(idx1 + NTOK);
  float* g1       = g0 + NTOK;
  int*   tok_slot = (int*)(g1 + NTOK);
  int*   idx_buf  = tok_slot + NTOK*2;

  // 1. merged prep: LN1 + QKV weight pack + Wo transpose
  prep_kernel<<<dim3(2304), 256, 0, stream>>>(x, ln1g, ln1b, h1hi, h1lo,
      Wq, Wk, Wv, Bqh, Bql, Wo, WoTh, WoTl);
  // 2. QKV projection (bf16x3 MFMA) with fused split/transpose LDS epilogue
  gemm_mfma3<1,12><<<dim3(64*12), 256, 0, stream>>>(h1hi, h1lo, Bqh, Bql,
      nullptr, nullptr, nullptr, Qhi, Qlo, Khi, Klo, Vthi, Vtlo, NTOK, 1536, DD);
  // 3. causal flash attention (KVBLK=128, all-bf16 inputs, defer-max)
  attn_mfma<<<dim3(32, 8), 512, 131072, stream>>>(Qhi, Qlo, Khi, Klo, Vthi, Vtlo, attnhi, attnlo);
  // 4. Wo projection + bias + residual -> x1
  gemm_mfma3<0,4><<<dim3(64*4), 256, 0, stream>>>(attnhi, attnlo, WoTh, WoTl,
      bo, x, x1, nullptr, nullptr, nullptr, nullptr, nullptr, nullptr, NTOK, DD, DD);
  // 5. fused LN2 + router
  routerln_kernel<<<dim3(NTOK/4), 256, 0, stream>>>(x1, ln2g, ln2b, Wg, bg, Wn, bn,
      h2b, idx0, idx1, g0, g1);
  // 6. merged expert-weight transpose + capacity scan
  transp_scan<<<dim3(513,1,NE), 256, 0, stream>>>(W1, W2, W1T, W2T,
      idx0, idx1, idx_buf, tok_slot);
  // 7+8. expert FFN, all 8 experts per launch (e = flat&7 -> one per XCD)
  gemm_mfma<1,1,1,4,3><<<dim3(8*16*16), 256, 0, stream>>>(
      h2b, W1T, b1, mid, idx_buf, CAPK, FF, DD);
  gemm_mfma<1,0,0,2,3><<<dim3(8*16*4), 256, 0, stream>>>(
      mid, W2T, b2, eoutb, nullptr, CAPK, DD, FF);
  // 9. combine + residual
  combine_kernel<<<dim3(NTOK), 128, 0, stream>>>(x1, eoutb, idx0, idx1, g0, g1, tok_slot, out);
}